// Round 1
// baseline (32070.108 us; speedup 1.0000x reference)
//
#include <hip/hip_runtime.h>
#include <stdint.h>
#include <stddef.h>

// ---------------- types ----------------
typedef __bf16 bf16;
typedef __bf16 bf16x8 __attribute__((ext_vector_type(8)));
typedef __bf16 bf16x4 __attribute__((ext_vector_type(4)));
typedef float  f32x4  __attribute__((ext_vector_type(4)));

// ---------------- problem constants ----------------
#define NB   64      // batch
#define NS   512     // seq len
#define NE   256     // embed dim
#define NH   256     // lstm hidden
#define NL   5       // lstm layers
#define NGC  256     // gcn hidden
#define FUSION 774   // 2H + GC + 6

__device__ __forceinline__ float sigm(float x) {
    return __fdividef(1.f, 1.f + __expf(-x));
}
__device__ __forceinline__ float tanh_(float x) {
    return __fdividef(2.f, 1.f + __expf(-2.f * x)) - 1.f;
}

// ---------------- embedding gather (f32 + bf16 copies) ----------------
__global__ void k_embed(const int* __restrict__ seq, const float* __restrict__ table,
                        float* __restrict__ ef, bf16* __restrict__ eb) {
    int t  = blockIdx.x * 256 + threadIdx.x;  // < 64*512*64
    int bs = t >> 6;
    int c4 = (t & 63) << 2;
    int row = seq[bs];
    f32x4 v = *(const f32x4*)(table + (size_t)row * NE + c4);
    *(f32x4*)(ef + (size_t)bs * NE + c4) = v;
    bf16x4 o;
    o[0] = (bf16)v[0]; o[1] = (bf16)v[1]; o[2] = (bf16)v[2]; o[3] = (bf16)v[3];
    *(bf16x4*)(eb + (size_t)bs * NE + c4) = o;
}

// ---------------- generic bf16 MFMA GEMM: C[M,N] = A[M,K](bf16) * W[N,K](f32)^T + bias ----------------
// tile 128x128, BK=64, 4 waves in 2x2 grid, each wave 64x64 via 4x4 16x16x32 frags.
__global__ __launch_bounds__(256, 2)
void k_gemm(const bf16* __restrict__ A, const float* __restrict__ W,
            const float* __restrict__ bias, void* __restrict__ Cout,
            int M, int N, int K, int out_bf16) {
    __shared__ bf16 sA[128 * 72];
    __shared__ bf16 sB[128 * 72];
    const int mblk = M >> 7;
    int bm = blockIdx.x % mblk;
    int bn = blockIdx.x / mblk;
    int m0 = bm << 7, n0 = bn << 7;
    int tid  = threadIdx.x;
    int wave = tid >> 6, lane = tid & 63;
    int wm = wave >> 1, wn = wave & 1;
    int l15 = lane & 15, quad = lane >> 4;

    f32x4 acc[4][4] = {};

    for (int k0 = 0; k0 < K; k0 += 64) {
        // stage A tile (bf16) 128x64
        {
            int r = tid >> 1, co = (tid & 1) * 32;
            const bf16* src = A + (size_t)(m0 + r) * K + k0 + co;
            bf16* dst = sA + r * 72 + co;
            *(uint4*)(dst +  0) = *(const uint4*)(src +  0);
            *(uint4*)(dst +  8) = *(const uint4*)(src +  8);
            *(uint4*)(dst + 16) = *(const uint4*)(src + 16);
            *(uint4*)(dst + 24) = *(const uint4*)(src + 24);
        }
        // stage W tile (f32 -> bf16) 128x64
        {
            int r = tid >> 1, co = (tid & 1) * 32;
            const float* src = W + (size_t)(n0 + r) * K + k0 + co;
            bf16* dst = sB + r * 72 + co;
#pragma unroll
            for (int i = 0; i < 32; i += 8) {
                f32x4 v0 = *(const f32x4*)(src + i);
                f32x4 v1 = *(const f32x4*)(src + i + 4);
                bf16x8 o;
                o[0]=(bf16)v0[0]; o[1]=(bf16)v0[1]; o[2]=(bf16)v0[2]; o[3]=(bf16)v0[3];
                o[4]=(bf16)v1[0]; o[5]=(bf16)v1[1]; o[6]=(bf16)v1[2]; o[7]=(bf16)v1[3];
                *(bf16x8*)(dst + i) = o;
            }
        }
        __syncthreads();
#pragma unroll
        for (int kk = 0; kk < 2; kk++) {
            bf16x8 af[4], bfr[4];
#pragma unroll
            for (int mt = 0; mt < 4; mt++)
                af[mt] = *(const bf16x8*)(sA + (wm * 64 + mt * 16 + l15) * 72 + kk * 32 + quad * 8);
#pragma unroll
            for (int nt = 0; nt < 4; nt++)
                bfr[nt] = *(const bf16x8*)(sB + (wn * 64 + nt * 16 + l15) * 72 + kk * 32 + quad * 8);
#pragma unroll
            for (int mt = 0; mt < 4; mt++)
#pragma unroll
                for (int nt = 0; nt < 4; nt++)
                    acc[mt][nt] = __builtin_amdgcn_mfma_f32_16x16x32_bf16(af[mt], bfr[nt], acc[mt][nt], 0, 0, 0);
        }
        __syncthreads();
    }
    // epilogue
#pragma unroll
    for (int mt = 0; mt < 4; mt++) {
#pragma unroll
        for (int nt = 0; nt < 4; nt++) {
            int col = n0 + wn * 64 + nt * 16 + l15;
            float bv = bias[col];
            int row0 = m0 + wm * 64 + mt * 16 + quad * 4;
#pragma unroll
            for (int r4 = 0; r4 < 4; r4++) {
                float v = acc[mt][nt][r4] + bv;
                size_t idx = (size_t)(row0 + r4) * N + col;
                if (out_bf16) ((bf16*)Cout)[idx] = (bf16)v;
                else          ((float*)Cout)[idx] = v;
            }
        }
    }
}

// ---------------- LSTM recurrence ----------------
// grid = 16 blocks x 512 threads. block = (dir d, j-slice of 32 hidden idx).
// Block owns Whh rows {g*256 + jbase + j} for 4 gates (128 rows), held in regs as B-frags.
// Per step: full h[64,256] (bf16) staged LDS -> MFMA gates -> LDS -> elementwise c/h -> publish h slice,
// 8-block/dir spin barrier via per-step device-scope counters.
__global__ __launch_bounds__(512, 2)
void k_lstm(const bf16* __restrict__ G,     // [32768][2048] gate inputs (x*Wih^T + b), both dirs
            const float* __restrict__ Whh,  // [2][1024][256] f32
            bf16* __restrict__ io_out,      // [32768][512]
            bf16* __restrict__ hbuf,        // [2][2][64][256] bf16
            int* __restrict__ cnt)          // [2][512]
{
    __shared__ float smem[128 * 68];  // 34.8 KB, aliased: gates [128][68] f32  OR  h [64][264] bf16
    bf16* hl = (bf16*)smem;
    float* gl = smem;

    const int blk = blockIdx.x;
    const int d = blk >> 3;
    const int jbase = (blk & 7) * 32;
    const int tid = threadIdx.x;
    const int wave = tid >> 6, lane = tid & 63;
    const int l15 = lane & 15, quad = lane >> 4;
    const int mt = wave & 3;   // M (batch) tile 0..3
    const int nh = wave >> 2;  // N half 0..1

    // ---- load resident weight B-fragments (bf16) ----
    bf16x8 Bf[4][8];
#pragma unroll
    for (int nt = 0; nt < 4; nt++) {
        int rl = nh * 64 + nt * 16 + l15;           // block-local row 0..127
        int gate = rl >> 5, jloc = rl & 31;
        const float* wrow = Whh + ((size_t)d * 1024 + gate * 256 + jbase + jloc) * 256;
#pragma unroll
        for (int kk = 0; kk < 8; kk++) {
            const float* p = wrow + kk * 32 + quad * 8;
            f32x4 v0 = *(const f32x4*)p;
            f32x4 v1 = *(const f32x4*)(p + 4);
            bf16x8 o;
            o[0]=(bf16)v0[0]; o[1]=(bf16)v0[1]; o[2]=(bf16)v0[2]; o[3]=(bf16)v0[3];
            o[4]=(bf16)v1[0]; o[5]=(bf16)v1[1]; o[6]=(bf16)v1[2]; o[7]=(bf16)v1[3];
            Bf[nt][kk] = o;
        }
    }

    // elementwise assignment: thread -> (j = tid>>4, batches eb0..eb0+3)
    const int ej = tid >> 4;
    const int eb0 = (tid & 15) * 4;
    const int jglob = jbase + ej;
    float cst[4] = {0.f, 0.f, 0.f, 0.f};

    for (int t = 0; t < NS; t++) {
        const int tt = d ? (NS - 1 - t) : t;

        // prefetch gate-input term (independent of h) before the barrier wait
        float gpre[4][4];
#pragma unroll
        for (int g4 = 0; g4 < 4; g4++)
#pragma unroll
            for (int bb = 0; bb < 4; bb++)
                gpre[g4][bb] = (float)G[(size_t)((eb0 + bb) * NS + tt) * 2048 + d * 1024 + g4 * 256 + jglob];

        f32x4 acc[4] = {};
        if (t > 0) {
            if (tid == 0) {
                while (__hip_atomic_load(&cnt[d * NS + (t - 1)], __ATOMIC_ACQUIRE,
                                         __HIP_MEMORY_SCOPE_AGENT) < 8) {
                    __builtin_amdgcn_s_sleep(2);
                }
            }
            __syncthreads();
            // copy full h[64][256] bf16 -> LDS (padded rows of 264)
            {
                int r = tid >> 3, s8 = tid & 7;
                const uint4* sp = (const uint4*)(hbuf + ((size_t)(d * 2 + ((t - 1) & 1)) * 64 + r) * 256 + s8 * 32);
                uint4* dp = (uint4*)(hl + r * 264 + s8 * 32);
                dp[0] = sp[0]; dp[1] = sp[1]; dp[2] = sp[2]; dp[3] = sp[3];
            }
            __syncthreads();
            // MFMA: gates[b][row] += sum_k h[b][k] * Whh[row][k]
            bf16x8 af[8];
#pragma unroll
            for (int kk = 0; kk < 8; kk++)
                af[kk] = *(const bf16x8*)(hl + (mt * 16 + l15) * 264 + kk * 32 + quad * 8);
#pragma unroll
            for (int nt = 0; nt < 4; nt++)
#pragma unroll
                for (int kk = 0; kk < 8; kk++)
                    acc[nt] = __builtin_amdgcn_mfma_f32_16x16x32_bf16(af[kk], Bf[nt][kk], acc[nt], 0, 0, 0);
            __syncthreads();  // h LDS consumed; smem will be reused as gates
        }

        // dump accumulators: gates_lds[row][batch], row stride 68 f32
#pragma unroll
        for (int nt = 0; nt < 4; nt++) {
            int row = nh * 64 + nt * 16 + l15;
            *(f32x4*)(gl + row * 68 + mt * 16 + quad * 4) = acc[nt];
        }
        __syncthreads();

        // elementwise gate math for (jglob, eb0..eb0+3)
        f32x4 gv[4];
#pragma unroll
        for (int g4 = 0; g4 < 4; g4++)
            gv[g4] = *(const f32x4*)(gl + (g4 * 32 + ej) * 68 + eb0);
#pragma unroll
        for (int bb = 0; bb < 4; bb++) {
            float pi = gv[0][bb] + gpre[0][bb];
            float pf = gv[1][bb] + gpre[1][bb];
            float pg = gv[2][bb] + gpre[2][bb];
            float po = gv[3][bb] + gpre[3][bb];
            float ig = sigm(pi), fg = sigm(pf), g2 = tanh_(pg), og = sigm(po);
            cst[bb] = fg * cst[bb] + ig * g2;
            float hh = og * tanh_(cst[bb]);
            bf16 hb = (bf16)hh;
            hbuf[((size_t)(d * 2 + (t & 1)) * 64 + (eb0 + bb)) * 256 + jglob] = hb;
            io_out[((size_t)(eb0 + bb) * NS + tt) * 512 + d * 256 + jglob] = hb;
        }

        __threadfence();
        __syncthreads();
        if (tid == 0)
            __hip_atomic_fetch_add(&cnt[d * NS + t], 1, __ATOMIC_RELEASE, __HIP_MEMORY_SCOPE_AGENT);
    }
}

// ---------------- GCN banded adjacency matmul -> bf16 ----------------
__global__ void k_banded(const float* __restrict__ x, const float* __restrict__ mask,
                         bf16* __restrict__ outb) {
    int t  = blockIdx.x * 256 + threadIdx.x;  // < 64*512*64
    int bs = t >> 6;
    int c4 = (t & 63) << 2;
    int s = bs & (NS - 1);
    float m  = mask[bs];
    float mn = (s < NS - 1) ? mask[bs + 1] : 0.f;
    float mp = (s > 0)      ? mask[bs - 1] : 0.f;
    float rs = m * (mp + mn) + 1e-8f;
    float cn = m * mn / rs;
    float cp = m * mp / rs;
    f32x4 vn = {}, vp = {};
    if (s < NS - 1) vn = *(const f32x4*)(x + (size_t)(bs + 1) * NGC + c4);
    if (s > 0)      vp = *(const f32x4*)(x + (size_t)(bs - 1) * NGC + c4);
    bf16x4 o;
#pragma unroll
    for (int i = 0; i < 4; i++) o[i] = (bf16)(cn * vn[i] + cp * vp[i]);
    *(bf16x4*)(outb + (size_t)bs * NGC + c4) = o;
}

// ---------------- GCN residual + layernorm + relu (one wave per row) ----------------
__global__ void k_gcnpost(const float* __restrict__ gemm_out, const float* __restrict__ x,
                          const float* __restrict__ gamma, const float* __restrict__ beta,
                          float* __restrict__ outx) {
    int row  = blockIdx.x * 4 + (threadIdx.x >> 6);
    int lane = threadIdx.x & 63;
    const float* h  = gemm_out + (size_t)row * NGC;
    const float* xr = x + (size_t)row * NGC;
    f32x4 hv = *(const f32x4*)(h + lane * 4);
    f32x4 xv = *(const f32x4*)(xr + lane * 4);
    f32x4 v;
#pragma unroll
    for (int i = 0; i < 4; i++) v[i] = hv[i] + xv[i];
    float sum = v[0] + v[1] + v[2] + v[3];
#pragma unroll
    for (int off = 32; off >= 1; off >>= 1) sum += __shfl_xor(sum, off);
    float mu = sum * (1.f / NGC);
    float sq = 0.f;
    f32x4 dv;
#pragma unroll
    for (int i = 0; i < 4; i++) { dv[i] = v[i] - mu; sq += dv[i] * dv[i]; }
#pragma unroll
    for (int off = 32; off >= 1; off >>= 1) sq += __shfl_xor(sq, off);
    float inv = rsqrtf(sq * (1.f / NGC) + 1e-5f);
    f32x4 o;
#pragma unroll
    for (int i = 0; i < 4; i++) {
        int c = lane * 4 + i;
        float y = dv[i] * inv * gamma[c] + beta[c];
        o[i] = fmaxf(y, 0.f);
    }
    *(f32x4*)(outx + (size_t)row * NGC + lane * 4) = o;
}

// ---------------- masked mean pooling ----------------
__global__ void k_pool_bf16(const bf16* __restrict__ src, const float* __restrict__ mask,
                            float* __restrict__ feat) {  // F = 512
    int b = blockIdx.x, f = threadIdx.x;
    float acc = 0.f, dm = 0.f;
    for (int t = 0; t < NS; t++) {
        float m = mask[b * NS + t];
        acc += m * (float)src[((size_t)b * NS + t) * 512 + f];
        dm += m;
    }
    feat[b * 512 + f] = acc / fmaxf(dm, 1e-8f);
}
__global__ void k_pool_f32(const float* __restrict__ src, const float* __restrict__ mask,
                           float* __restrict__ feat) {  // F = 256
    int b = blockIdx.x, f = threadIdx.x;
    float acc = 0.f, dm = 0.f;
    for (int t = 0; t < NS; t++) {
        float m = mask[b * NS + t];
        acc += m * src[((size_t)b * NS + t) * NGC + f];
        dm += m;
    }
    feat[b * NGC + f] = acc / fmaxf(dm, 1e-8f);
}

// ---------------- fused head: concat -> fc1 relu -> fc2 relu -> two heads ----------------
__global__ __launch_bounds__(512)
void k_head(const float* __restrict__ lfeat, const float* __restrict__ gfeat,
            const float* __restrict__ aux,
            const float* __restrict__ fc1W, const float* __restrict__ fc1b,
            const float* __restrict__ fc2W, const float* __restrict__ fc2b,
            const float* __restrict__ h0W, const float* __restrict__ h0b,
            const float* __restrict__ h1W, const float* __restrict__ h1b,
            float* __restrict__ out) {
    __shared__ float fused[FUSION];
    __shared__ float s1[512];
    __shared__ float s2[256];
    int m = blockIdx.x, tid = threadIdx.x;
    if (tid < 512) fused[tid] = lfeat[m * 512 + tid];
    if (tid < 256) fused[512 + tid] = gfeat[m * 256 + tid];
    if (tid < 6)   fused[768 + tid] = aux[m * 6 + tid];
    __syncthreads();
    {
        float a = fc1b[tid];
        const float* w = fc1W + (size_t)tid * FUSION;
        for (int k = 0; k < FUSION; k++) a += w[k] * fused[k];
        s1[tid] = fmaxf(a, 0.f);
    }
    __syncthreads();
    if (tid < 256) {
        float a = fc2b[tid];
        const float* w = fc2W + (size_t)tid * 512;
        for (int k = 0; k < 512; k++) a += w[k] * s1[k];
        s2[tid] = fmaxf(a, 0.f);
    }
    __syncthreads();
    if (tid < 15) {
        if (tid < 10) {
            float a = h0b[tid];
            const float* w = h0W + (size_t)tid * 256;
            for (int k = 0; k < 256; k++) a += w[k] * s2[k];
            out[m * 10 + tid] = a;
        } else {
            int n = tid - 10;
            float a = h1b[n];
            const float* w = h1W + (size_t)n * 256;
            for (int k = 0; k < 256; k++) a += w[k] * s2[k];
            out[640 + m * 5 + n] = a;
        }
    }
}

// ---------------- host launcher ----------------
extern "C" void kernel_launch(void* const* d_in, const int* in_sizes, int n_in,
                              void* d_out, int out_size, void* d_ws, size_t ws_size,
                              hipStream_t stream) {
    const int*   seq   = (const int*)d_in[0];
    const float* mask  = (const float*)d_in[1];
    const float* aux   = (const float*)d_in[2];
    const float* table = (const float*)d_in[3];
    const float* Wih0  = (const float*)d_in[4];
    const float* Whh0  = (const float*)d_in[5];
    const float* b0    = (const float*)d_in[6];
    const float* WihL  = (const float*)d_in[7];
    const float* WhhL  = (const float*)d_in[8];
    const float* bL    = (const float*)d_in[9];
    const float* gcnW  = (const float*)d_in[10];
    const float* gcnb  = (const float*)d_in[11];
    const float* gcnG  = (const float*)d_in[12];
    const float* gcnBe = (const float*)d_in[13];
    const float* fc1W  = (const float*)d_in[14];
    const float* fc1b  = (const float*)d_in[15];
    const float* fc2W  = (const float*)d_in[16];
    const float* fc2b  = (const float*)d_in[17];
    const float* h0W   = (const float*)d_in[18];
    const float* h0b   = (const float*)d_in[19];
    const float* h1W   = (const float*)d_in[20];
    const float* h1b   = (const float*)d_in[21];
    float* outp = (float*)d_out;

    char* ws = (char*)d_ws;
    const size_t MROWS = (size_t)NB * NS;          // 32768
    float* emb_f32 = (float*)(ws + 0);             // 33.55 MB
    bf16*  emb_b   = (bf16*) (ws + 33554432);      // 16.78 MB
    bf16*  io0     = (bf16*) (ws + 50331648);      // 33.55 MB
    bf16*  io1     = (bf16*) (ws + 83886080);      // 33.55 MB
    char*  Greg    =          ws + 117440512;      // 134.22 MB (G; GCN scratch aliases here)
    bf16*  G       = (bf16*)  Greg;
    bf16*  hbuf    = (bf16*) (ws + 251658240);     // 128 KB
    int*   cnt     = (int*)  (ws + 251789312);     // 20 KB  [5][2][512]
    float* lfeat   = (float*)(ws + 251809792);     // 128 KB
    float* gfeat   = (float*)(ws + 251940864);     // 64 KB
    // GCN aliases (used before G):
    float* gcnA  = (float*)(Greg + 0);
    float* gcnB_ = (float*)(Greg + 33554432);
    float* ggemm = (float*)(Greg + 67108864);
    bf16*  gtmp  = (bf16*) (Greg + 100663296);
    (void)ws_size; (void)n_in; (void)in_sizes; (void)out_size;

    hipMemsetAsync(cnt, 0, NL * 2 * NS * sizeof(int), stream);

    // embedding
    k_embed<<<dim3(8192), dim3(256), 0, stream>>>(seq, table, emb_f32, emb_b);

    // ---- GCN stack (independent of LSTM; uses G region as scratch) ----
    const float* xcur = emb_f32;
    float* xnxt[3] = {gcnA, gcnB_, gcnA};
    for (int i = 0; i < 3; i++) {
        k_banded<<<dim3(8192), dim3(256), 0, stream>>>(xcur, mask, gtmp);
        k_gemm<<<dim3((MROWS / 128) * (NGC / 128)), dim3(256), 0, stream>>>(
            gtmp, gcnW + (size_t)i * NGC * NGC, gcnb + i * NGC, ggemm,
            (int)MROWS, NGC, NGC, 0);
        k_gcnpost<<<dim3(8192), dim3(256), 0, stream>>>(
            ggemm, xcur, gcnG + i * NGC, gcnBe + i * NGC, xnxt[i]);
        xcur = xnxt[i];
    }
    k_pool_f32<<<dim3(NB), dim3(NGC), 0, stream>>>(xcur, mask, gfeat);

    // ---- BiLSTM stack ----
    const bf16* Xin = emb_b;
    int Kin = NE;
    bf16* ios[2] = {io0, io1};
    for (int l = 0; l < NL; l++) {
        const float* wih  = l ? (WihL + (size_t)(l - 1) * 2 * 1024 * 512) : Wih0;
        const float* whh  = l ? (WhhL + (size_t)(l - 1) * 2 * 1024 * 256) : Whh0;
        const float* bias = l ? (bL + (size_t)(l - 1) * 2048) : b0;
        k_gemm<<<dim3((MROWS / 128) * (2048 / 128)), dim3(256), 0, stream>>>(
            Xin, wih, bias, G, (int)MROWS, 2048, Kin, 1);
        bf16* lio = ios[l & 1];
        k_lstm<<<dim3(16), dim3(512), 0, stream>>>(G, whh, lio, hbuf, cnt + l * 2 * NS);
        Xin = lio;
        Kin = 512;
    }
    k_pool_bf16<<<dim3(NB), dim3(512), 0, stream>>>(ios[(NL - 1) & 1], mask, lfeat);

    // ---- fused head ----
    k_head<<<dim3(NB), dim3(512), 0, stream>>>(
        lfeat, gfeat, aux, fc1W, fc1b, fc2W, fc2b, h0W, h0b, h1W, h1b, outp);
}

// Round 2
// 17840.253 us; speedup vs baseline: 1.7976x; 1.7976x over previous
//
#include <hip/hip_runtime.h>
#include <stdint.h>
#include <stddef.h>

// ---------------- types ----------------
typedef __bf16 bf16;
typedef __bf16 bf16x8 __attribute__((ext_vector_type(8)));
typedef __bf16 bf16x4 __attribute__((ext_vector_type(4)));
typedef float  f32x4  __attribute__((ext_vector_type(4)));

// ---------------- problem constants ----------------
#define NB   64      // batch
#define NS   512     // seq len
#define NE   256     // embed dim
#define NH   256     // lstm hidden
#define NL   5       // lstm layers
#define NGC  256     // gcn hidden
#define FUSION 774   // 2H + GC + 6

__device__ __forceinline__ float sigm(float x) {
    return __fdividef(1.f, 1.f + __expf(-x));
}
__device__ __forceinline__ float tanh_(float x) {
    return __fdividef(2.f, 1.f + __expf(-2.f * x)) - 1.f;
}

// ---------------- embedding gather (f32 + bf16 copies) ----------------
__global__ void k_embed(const int* __restrict__ seq, const float* __restrict__ table,
                        float* __restrict__ ef, bf16* __restrict__ eb) {
    int t  = blockIdx.x * 256 + threadIdx.x;  // < 64*512*64
    int bs = t >> 6;
    int c4 = (t & 63) << 2;
    int row = seq[bs];
    f32x4 v = *(const f32x4*)(table + (size_t)row * NE + c4);
    *(f32x4*)(ef + (size_t)bs * NE + c4) = v;
    bf16x4 o;
    o[0] = (bf16)v[0]; o[1] = (bf16)v[1]; o[2] = (bf16)v[2]; o[3] = (bf16)v[3];
    *(bf16x4*)(eb + (size_t)bs * NE + c4) = o;
}

// ---------------- generic bf16 MFMA GEMM: C[M,N] = A[M,K](bf16) * W[N,K](f32)^T + bias ----------------
// out_mode: 0 = f32 [M,N]; 1 = bf16 [M,N]; 2 = bf16 t-major [ (m%NS)*64 + m/NS ][2048]
__global__ __launch_bounds__(256, 2)
void k_gemm(const bf16* __restrict__ A, const float* __restrict__ W,
            const float* __restrict__ bias, void* __restrict__ Cout,
            int M, int N, int K, int out_mode) {
    __shared__ bf16 sA[128 * 72];
    __shared__ bf16 sB[128 * 72];
    const int mblk = M >> 7;
    int bm = blockIdx.x % mblk;
    int bn = blockIdx.x / mblk;
    int m0 = bm << 7, n0 = bn << 7;
    int tid  = threadIdx.x;
    int wave = tid >> 6, lane = tid & 63;
    int wm = wave >> 1, wn = wave & 1;
    int l15 = lane & 15, quad = lane >> 4;

    f32x4 acc[4][4] = {};

    for (int k0 = 0; k0 < K; k0 += 64) {
        {
            int r = tid >> 1, co = (tid & 1) * 32;
            const bf16* src = A + (size_t)(m0 + r) * K + k0 + co;
            bf16* dst = sA + r * 72 + co;
            *(uint4*)(dst +  0) = *(const uint4*)(src +  0);
            *(uint4*)(dst +  8) = *(const uint4*)(src +  8);
            *(uint4*)(dst + 16) = *(const uint4*)(src + 16);
            *(uint4*)(dst + 24) = *(const uint4*)(src + 24);
        }
        {
            int r = tid >> 1, co = (tid & 1) * 32;
            const float* src = W + (size_t)(n0 + r) * K + k0 + co;
            bf16* dst = sB + r * 72 + co;
#pragma unroll
            for (int i = 0; i < 32; i += 8) {
                f32x4 v0 = *(const f32x4*)(src + i);
                f32x4 v1 = *(const f32x4*)(src + i + 4);
                bf16x8 o;
                o[0]=(bf16)v0[0]; o[1]=(bf16)v0[1]; o[2]=(bf16)v0[2]; o[3]=(bf16)v0[3];
                o[4]=(bf16)v1[0]; o[5]=(bf16)v1[1]; o[6]=(bf16)v1[2]; o[7]=(bf16)v1[3];
                *(bf16x8*)(dst + i) = o;
            }
        }
        __syncthreads();
#pragma unroll
        for (int kk = 0; kk < 2; kk++) {
            bf16x8 af[4], bfr[4];
#pragma unroll
            for (int mt = 0; mt < 4; mt++)
                af[mt] = *(const bf16x8*)(sA + (wm * 64 + mt * 16 + l15) * 72 + kk * 32 + quad * 8);
#pragma unroll
            for (int nt = 0; nt < 4; nt++)
                bfr[nt] = *(const bf16x8*)(sB + (wn * 64 + nt * 16 + l15) * 72 + kk * 32 + quad * 8);
#pragma unroll
            for (int mt = 0; mt < 4; mt++)
#pragma unroll
                for (int nt = 0; nt < 4; nt++)
                    acc[mt][nt] = __builtin_amdgcn_mfma_f32_16x16x32_bf16(af[mt], bfr[nt], acc[mt][nt], 0, 0, 0);
        }
        __syncthreads();
    }
#pragma unroll
    for (int mt = 0; mt < 4; mt++) {
#pragma unroll
        for (int nt = 0; nt < 4; nt++) {
            int col = n0 + wn * 64 + nt * 16 + l15;
            float bv = bias[col];
            int row0 = m0 + wm * 64 + mt * 16 + quad * 4;
#pragma unroll
            for (int r4 = 0; r4 < 4; r4++) {
                float v = acc[mt][nt][r4] + bv;
                int r = row0 + r4;
                if (out_mode == 2) {
                    int ro = ((r & (NS - 1)) << 6) | (r >> 9);
                    ((bf16*)Cout)[(size_t)ro * 2048 + col] = (bf16)v;
                } else if (out_mode == 1) {
                    ((bf16*)Cout)[(size_t)r * N + col] = (bf16)v;
                } else {
                    ((float*)Cout)[(size_t)r * N + col] = v;
                }
            }
        }
    }
}

// ---------------- Whh pre-pack: f32 [L][2][1024][256] -> bf16 MFMA-fragment-major ----------------
// cell (d,w,nt,kt) = 512 elems: lane*8 + e, lane = quad*16 + l15,
// covering rows g*256 + w*32 + hi*16 + l15 (nt = g*2+hi), k = kt*32 + quad*8 + e.
__global__ void k_prep(const float* __restrict__ Whh0, const float* __restrict__ WhhL,
                       bf16* __restrict__ Wp) {
    int t = blockIdx.x * 256 + threadIdx.x;   // < 5*2*1024*32 = 327680
    int k8 = (t & 31) * 8;
    int row = (t >> 5) & 1023;
    int d   = (t >> 15) & 1;
    int layer = t >> 16;
    const float* src = (layer == 0)
        ? (Whh0 + ((size_t)d * 1024 + row) * 256 + k8)
        : (WhhL + ((((size_t)(layer - 1) * 2 + d) * 1024 + row) * 256 + k8));
    int g = row >> 8, r8 = row & 255;
    int w = r8 >> 5, hi = (r8 >> 4) & 1, l15 = r8 & 15;
    int nt = g * 2 + hi, kt = k8 >> 5, quad = (k8 >> 3) & 3;
    int lane = quad * 16 + l15;
    int fi = (w * 8 + nt) * 8 + kt;
    f32x4 v0 = ((const f32x4*)src)[0];
    f32x4 v1 = ((const f32x4*)src)[1];
    bf16x8 o;
    o[0]=(bf16)v0[0]; o[1]=(bf16)v0[1]; o[2]=(bf16)v0[2]; o[3]=(bf16)v0[3];
    o[4]=(bf16)v1[0]; o[5]=(bf16)v1[1]; o[6]=(bf16)v1[2]; o[7]=(bf16)v1[3];
    *(bf16x8*)(Wp + ((((size_t)layer * 2 + d) * 512 + fi) * 512 + lane * 8)) = o;
}

// ---------------- LSTM recurrence, batch-partitioned, zero inter-block comm ----------------
// grid = 8 blocks x 512 threads; block = (dir d, batch group of 16).
// Whh: 16 cells/wave register-resident (kt 0..1), kt 2..7 streamed from L2 each step.
// G is t-major [S][64][2048]; 32KB/step staged to LDS coalesced.
// Per lane: all 4 gates of (b,j) land in-register -> elementwise fully local.
__global__ __launch_bounds__(512, 2)
void k_lstm_r(const bf16* __restrict__ G,    // [S][64][2048]
              const bf16* __restrict__ Wp,   // [2][512][512] packed cells
              bf16* __restrict__ io_out)     // [64][S][512]
{
    __shared__ bf16 hb[2][16 * 280];   // h dbuf, row stride 280 elems (16B-aligned rows)
    __shared__ bf16 gb[16 * 1048];     // G staging, row stride 1048 elems

    const int d  = blockIdx.x & 1;
    const int bg = blockIdx.x >> 1;
    const int tid = threadIdx.x;
    const int w = tid >> 6, lane = tid & 63;
    const int l15 = lane & 15, quad = lane >> 4;
    const int b0g = bg * 16;

    const bf16* wbase = Wp + ((size_t)d * 512 + w * 64) * 512 + lane * 8;

    // register-resident weight cells: kt 0..1 for all 8 n-tiles (64 VGPR)
    bf16x8 Wr[8][2];
#pragma unroll
    for (int nt = 0; nt < 8; nt++)
#pragma unroll
        for (int kt = 0; kt < 2; kt++)
            Wr[nt][kt] = *(const bf16x8*)(wbase + (nt * 8 + kt) * 512);

    float cst[2][4] = {{0.f,0.f,0.f,0.f},{0.f,0.f,0.f,0.f}};

    const int gbl = tid >> 5;            // local batch handled by this thread's G copy
    const int gwi = (tid & 31) * 32;     // element offset within the 1024-elem dir half
    bf16* gdst = gb + gbl * 1048 + gwi;

    for (int t = 0; t < NS; t++) {
        const int tt = d ? (NS - 1 - t) : t;
        const int rb = (t + 1) & 1, wbuf = t & 1;

        // 1. issue G(t) loads (longest latency first; consumed after MFMA)
        const bf16* gsrc = G + ((size_t)(tt * 64 + b0g + gbl) * 2048 + d * 1024 + gwi);
        uint4 g0 = ((const uint4*)gsrc)[0];
        uint4 g1 = ((const uint4*)gsrc)[1];
        uint4 g2 = ((const uint4*)gsrc)[2];
        uint4 g3 = ((const uint4*)gsrc)[3];

        f32x4 acc[8] = {};
        if (t > 0) {
            // prefetch first streamed kt
            bf16x8 Ws0[8], Ws1[8];
#pragma unroll
            for (int nt = 0; nt < 8; nt++)
                Ws0[nt] = *(const bf16x8*)(wbase + (nt * 8 + 2) * 512);
            // A fragments: h_{t-1}[b=l15][k]
            const bf16* hrow = hb[rb] + l15 * 280 + quad * 8;
            bf16x8 af[8];
#pragma unroll
            for (int kt = 0; kt < 8; kt++)
                af[kt] = *(const bf16x8*)(hrow + kt * 32);
            // resident rounds
#pragma unroll
            for (int kt = 0; kt < 2; kt++)
#pragma unroll
                for (int nt = 0; nt < 8; nt++)
                    acc[nt] = __builtin_amdgcn_mfma_f32_16x16x32_bf16(af[kt], Wr[nt][kt], acc[nt], 0, 0, 0);
            // streamed rounds kt 2..7, double-buffered prefetch
#pragma unroll
            for (int kt = 2; kt < 8; kt++) {
                const bf16x8* cur = (kt & 1) ? Ws1 : Ws0;
                bf16x8* nxt = (kt & 1) ? Ws0 : Ws1;
                if (kt < 7) {
#pragma unroll
                    for (int nt = 0; nt < 8; nt++)
                        nxt[nt] = *(const bf16x8*)(wbase + (nt * 8 + kt + 1) * 512);
                }
#pragma unroll
                for (int nt = 0; nt < 8; nt++)
                    acc[nt] = __builtin_amdgcn_mfma_f32_16x16x32_bf16(af[kt], cur[nt], acc[nt], 0, 0, 0);
            }
        }

        // 2. land G in LDS
        ((uint4*)gdst)[0] = g0; ((uint4*)gdst)[1] = g1;
        ((uint4*)gdst)[2] = g2; ((uint4*)gdst)[3] = g3;
        __syncthreads();   // G visible to all waves; hb[rb] reads complete

        // 3. elementwise gates -> c,h (all 4 gates of (b,j) are lane-local)
        bf16* hw = hb[wbuf];
#pragma unroll
        for (int hi = 0; hi < 2; hi++) {
            const int j = w * 32 + hi * 16 + l15;
#pragma unroll
            for (int r = 0; r < 4; r++) {
                const int bl = quad * 4 + r;
                const bf16* grow = gb + bl * 1048 + j;
                float gi = acc[0 + hi][r] + (float)grow[0];
                float gf = acc[2 + hi][r] + (float)grow[256];
                float gg = acc[4 + hi][r] + (float)grow[512];
                float go = acc[6 + hi][r] + (float)grow[768];
                float ig = sigm(gi), fg = sigm(gf), gc = tanh_(gg), og = sigm(go);
                float c = fg * cst[hi][r] + ig * gc;
                cst[hi][r] = c;
                float hh = og * tanh_(c);
                bf16 hv = (bf16)hh;
                hw[bl * 280 + j] = hv;
                io_out[((size_t)(b0g + bl) * NS + tt) * 512 + d * 256 + j] = hv;
            }
        }
        __syncthreads();   // h(t) published in LDS for next step
    }
}

// ---------------- GCN banded adjacency matmul -> bf16 ----------------
__global__ void k_banded(const float* __restrict__ x, const float* __restrict__ mask,
                         bf16* __restrict__ outb) {
    int t  = blockIdx.x * 256 + threadIdx.x;  // < 64*512*64
    int bs = t >> 6;
    int c4 = (t & 63) << 2;
    int s = bs & (NS - 1);
    float m  = mask[bs];
    float mn = (s < NS - 1) ? mask[bs + 1] : 0.f;
    float mp = (s > 0)      ? mask[bs - 1] : 0.f;
    float rs = m * (mp + mn) + 1e-8f;
    float cn = m * mn / rs;
    float cp = m * mp / rs;
    f32x4 vn = {}, vp = {};
    if (s < NS - 1) vn = *(const f32x4*)(x + (size_t)(bs + 1) * NGC + c4);
    if (s > 0)      vp = *(const f32x4*)(x + (size_t)(bs - 1) * NGC + c4);
    bf16x4 o;
#pragma unroll
    for (int i = 0; i < 4; i++) o[i] = (bf16)(cn * vn[i] + cp * vp[i]);
    *(bf16x4*)(outb + (size_t)bs * NGC + c4) = o;
}

// ---------------- GCN residual + layernorm + relu (one wave per row) ----------------
__global__ void k_gcnpost(const float* __restrict__ gemm_out, const float* __restrict__ x,
                          const float* __restrict__ gamma, const float* __restrict__ beta,
                          float* __restrict__ outx) {
    int row  = blockIdx.x * 4 + (threadIdx.x >> 6);
    int lane = threadIdx.x & 63;
    const float* h  = gemm_out + (size_t)row * NGC;
    const float* xr = x + (size_t)row * NGC;
    f32x4 hv = *(const f32x4*)(h + lane * 4);
    f32x4 xv = *(const f32x4*)(xr + lane * 4);
    f32x4 v;
#pragma unroll
    for (int i = 0; i < 4; i++) v[i] = hv[i] + xv[i];
    float sum = v[0] + v[1] + v[2] + v[3];
#pragma unroll
    for (int off = 32; off >= 1; off >>= 1) sum += __shfl_xor(sum, off);
    float mu = sum * (1.f / NGC);
    float sq = 0.f;
    f32x4 dv;
#pragma unroll
    for (int i = 0; i < 4; i++) { dv[i] = v[i] - mu; sq += dv[i] * dv[i]; }
#pragma unroll
    for (int off = 32; off >= 1; off >>= 1) sq += __shfl_xor(sq, off);
    float inv = rsqrtf(sq * (1.f / NGC) + 1e-5f);
    f32x4 o;
#pragma unroll
    for (int i = 0; i < 4; i++) {
        int c = lane * 4 + i;
        float y = dv[i] * inv * gamma[c] + beta[c];
        o[i] = fmaxf(y, 0.f);
    }
    *(f32x4*)(outx + (size_t)row * NGC + lane * 4) = o;
}

// ---------------- masked mean pooling ----------------
__global__ void k_pool_bf16(const bf16* __restrict__ src, const float* __restrict__ mask,
                            float* __restrict__ feat) {  // F = 512
    int b = blockIdx.x, f = threadIdx.x;
    float acc = 0.f, dm = 0.f;
    for (int t = 0; t < NS; t++) {
        float m = mask[b * NS + t];
        acc += m * (float)src[((size_t)b * NS + t) * 512 + f];
        dm += m;
    }
    feat[b * 512 + f] = acc / fmaxf(dm, 1e-8f);
}
__global__ void k_pool_f32(const float* __restrict__ src, const float* __restrict__ mask,
                           float* __restrict__ feat) {  // F = 256
    int b = blockIdx.x, f = threadIdx.x;
    float acc = 0.f, dm = 0.f;
    for (int t = 0; t < NS; t++) {
        float m = mask[b * NS + t];
        acc += m * src[((size_t)b * NS + t) * NGC + f];
        dm += m;
    }
    feat[b * NGC + f] = acc / fmaxf(dm, 1e-8f);
}

// ---------------- fused head ----------------
__global__ __launch_bounds__(512)
void k_head(const float* __restrict__ lfeat, const float* __restrict__ gfeat,
            const float* __restrict__ aux,
            const float* __restrict__ fc1W, const float* __restrict__ fc1b,
            const float* __restrict__ fc2W, const float* __restrict__ fc2b,
            const float* __restrict__ h0W, const float* __restrict__ h0b,
            const float* __restrict__ h1W, const float* __restrict__ h1b,
            float* __restrict__ out) {
    __shared__ float fused[FUSION];
    __shared__ float s1[512];
    __shared__ float s2[256];
    int m = blockIdx.x, tid = threadIdx.x;
    if (tid < 512) fused[tid] = lfeat[m * 512 + tid];
    if (tid < 256) fused[512 + tid] = gfeat[m * 256 + tid];
    if (tid < 6)   fused[768 + tid] = aux[m * 6 + tid];
    __syncthreads();
    {
        float a = fc1b[tid];
        const float* w = fc1W + (size_t)tid * FUSION;
        for (int k = 0; k < FUSION; k++) a += w[k] * fused[k];
        s1[tid] = fmaxf(a, 0.f);
    }
    __syncthreads();
    if (tid < 256) {
        float a = fc2b[tid];
        const float* w = fc2W + (size_t)tid * 512;
        for (int k = 0; k < 512; k++) a += w[k] * s1[k];
        s2[tid] = fmaxf(a, 0.f);
    }
    __syncthreads();
    if (tid < 15) {
        if (tid < 10) {
            float a = h0b[tid];
            const float* w = h0W + (size_t)tid * 256;
            for (int k = 0; k < 256; k++) a += w[k] * s2[k];
            out[m * 10 + tid] = a;
        } else {
            int n = tid - 10;
            float a = h1b[n];
            const float* w = h1W + (size_t)n * 256;
            for (int k = 0; k < 256; k++) a += w[k] * s2[k];
            out[640 + m * 5 + n] = a;
        }
    }
}

// ---------------- host launcher ----------------
extern "C" void kernel_launch(void* const* d_in, const int* in_sizes, int n_in,
                              void* d_out, int out_size, void* d_ws, size_t ws_size,
                              hipStream_t stream) {
    const int*   seq   = (const int*)d_in[0];
    const float* mask  = (const float*)d_in[1];
    const float* aux   = (const float*)d_in[2];
    const float* table = (const float*)d_in[3];
    const float* Wih0  = (const float*)d_in[4];
    const float* Whh0  = (const float*)d_in[5];
    const float* b0    = (const float*)d_in[6];
    const float* WihL  = (const float*)d_in[7];
    const float* WhhL  = (const float*)d_in[8];
    const float* bL    = (const float*)d_in[9];
    const float* gcnW  = (const float*)d_in[10];
    const float* gcnb  = (const float*)d_in[11];
    const float* gcnG  = (const float*)d_in[12];
    const float* gcnBe = (const float*)d_in[13];
    const float* fc1W  = (const float*)d_in[14];
    const float* fc1b  = (const float*)d_in[15];
    const float* fc2W  = (const float*)d_in[16];
    const float* fc2b  = (const float*)d_in[17];
    const float* h0W   = (const float*)d_in[18];
    const float* h0b   = (const float*)d_in[19];
    const float* h1W   = (const float*)d_in[20];
    const float* h1b   = (const float*)d_in[21];
    float* outp = (float*)d_out;

    char* ws = (char*)d_ws;
    const size_t MROWS = (size_t)NB * NS;          // 32768
    float* emb_f32 = (float*)(ws + 0);             // 33.55 MB
    bf16*  emb_b   = (bf16*) (ws + 33554432);      // 16.78 MB (dead after L0 gemm)
    bf16*  Wp      = (bf16*) (ws + 33554432);      // 2.62 MB, aliases emb_b (written after L0 gemm)
    bf16*  io0     = (bf16*) (ws + 50331648);      // 33.55 MB
    bf16*  io1     = (bf16*) (ws + 83886080);      // 33.55 MB
    char*  Greg    =          ws + 117440512;      // 134.22 MB (G; GCN scratch aliases here)
    bf16*  G       = (bf16*)  Greg;
    float* lfeat   = (float*)(ws + 251658240);     // 128 KB
    float* gfeat   = (float*)(ws + 251789312);     // 64 KB
    // GCN aliases (used before G):
    float* gcnA  = (float*)(Greg + 0);
    float* gcnB_ = (float*)(Greg + 33554432);
    float* ggemm = (float*)(Greg + 67108864);
    bf16*  gtmp  = (bf16*) (Greg + 100663296);
    (void)ws_size; (void)n_in; (void)in_sizes; (void)out_size;

    // embedding
    k_embed<<<dim3(8192), dim3(256), 0, stream>>>(seq, table, emb_f32, emb_b);

    // ---- GCN stack ----
    const float* xcur = emb_f32;
    float* xnxt[3] = {gcnA, gcnB_, gcnA};
    for (int i = 0; i < 3; i++) {
        k_banded<<<dim3(8192), dim3(256), 0, stream>>>(xcur, mask, gtmp);
        k_gemm<<<dim3((MROWS / 128) * (NGC / 128)), dim3(256), 0, stream>>>(
            gtmp, gcnW + (size_t)i * NGC * NGC, gcnb + i * NGC, ggemm,
            (int)MROWS, NGC, NGC, 0);
        k_gcnpost<<<dim3(8192), dim3(256), 0, stream>>>(
            ggemm, xcur, gcnG + i * NGC, gcnBe + i * NGC, xnxt[i]);
        xcur = xnxt[i];
    }
    k_pool_f32<<<dim3(NB), dim3(NGC), 0, stream>>>(xcur, mask, gfeat);

    // ---- BiLSTM stack ----
    const bf16* Xin = emb_b;
    int Kin = NE;
    bf16* ios[2] = {io0, io1};
    for (int l = 0; l < NL; l++) {
        const float* wih  = l ? (WihL + (size_t)(l - 1) * 2 * 1024 * 512) : Wih0;
        const float* bias = l ? (bL + (size_t)(l - 1) * 2048) : b0;
        k_gemm<<<dim3((MROWS / 128) * (2048 / 128)), dim3(256), 0, stream>>>(
            Xin, wih, bias, G, (int)MROWS, 2048, Kin, 2);
        if (l == 0) {
            // emb_b consumed; pack all layers' Whh into fragment-major bf16
            k_prep<<<dim3(1280), dim3(256), 0, stream>>>(Whh0, WhhL, Wp);
        }
        bf16* lio = ios[l & 1];
        k_lstm_r<<<dim3(8), dim3(512), 0, stream>>>(G, Wp + (size_t)l * 524288, lio);
        Xin = lio;
        Kin = 512;
    }
    k_pool_bf16<<<dim3(NB), dim3(512), 0, stream>>>(ios[(NL - 1) & 1], mask, lfeat);

    // ---- fused head ----
    k_head<<<dim3(NB), dim3(512), 0, stream>>>(
        lfeat, gfeat, aux, fc1W, fc1b, fc2W, fc2b, h0W, h0b, h1W, h1b, outp);
}

// Round 3
// 10713.110 us; speedup vs baseline: 2.9935x; 1.6653x over previous
//
#include <hip/hip_runtime.h>
#include <stdint.h>
#include <stddef.h>

// ---------------- types ----------------
typedef __bf16 bf16;
typedef __bf16 bf16x8 __attribute__((ext_vector_type(8)));
typedef __bf16 bf16x4 __attribute__((ext_vector_type(4)));
typedef float  f32x4  __attribute__((ext_vector_type(4)));
typedef int    v4i    __attribute__((ext_vector_type(4)));

// ---------------- problem constants ----------------
#define NB   64      // batch
#define NS   512     // seq len
#define NE   256     // embed dim
#define NH   256     // lstm hidden
#define NL   5       // lstm layers
#define NGC  256     // gcn hidden
#define FUSION 774   // 2H + GC + 6

__device__ __forceinline__ float sigm(float x) {
    return __fdividef(1.f, 1.f + __expf(-x));
}
__device__ __forceinline__ float tanh_(float x) {
    return __fdividef(2.f, 1.f + __expf(-2.f * x)) - 1.f;
}

// ---------------- embedding gather (f32 + bf16 copies) ----------------
__global__ void k_embed(const int* __restrict__ seq, const float* __restrict__ table,
                        float* __restrict__ ef, bf16* __restrict__ eb) {
    int t  = blockIdx.x * 256 + threadIdx.x;  // < 64*512*64
    int bs = t >> 6;
    int c4 = (t & 63) << 2;
    int row = seq[bs];
    f32x4 v = *(const f32x4*)(table + (size_t)row * NE + c4);
    *(f32x4*)(ef + (size_t)bs * NE + c4) = v;
    bf16x4 o;
    o[0] = (bf16)v[0]; o[1] = (bf16)v[1]; o[2] = (bf16)v[2]; o[3] = (bf16)v[3];
    *(bf16x4*)(eb + (size_t)bs * NE + c4) = o;
}

// ---------------- generic bf16 MFMA GEMM: C[M,N] = A[M,K](bf16) * W[N,K](f32)^T + bias ----------------
// out_mode: 0 = f32 [M,N]; 3 = bf16 gate-interleaved [tt][b][d][j][g] with
//           m = b*NS+tt, col = d*1024 + g*256 + j
__global__ __launch_bounds__(256, 2)
void k_gemm(const bf16* __restrict__ A, const float* __restrict__ W,
            const float* __restrict__ bias, void* __restrict__ Cout,
            int M, int N, int K, int out_mode) {
    __shared__ bf16 sA[128 * 72];
    __shared__ bf16 sB[128 * 72];
    const int mblk = M >> 7;
    int bm = blockIdx.x % mblk;
    int bn = blockIdx.x / mblk;
    int m0 = bm << 7, n0 = bn << 7;
    int tid  = threadIdx.x;
    int wave = tid >> 6, lane = tid & 63;
    int wm = wave >> 1, wn = wave & 1;
    int l15 = lane & 15, quad = lane >> 4;

    f32x4 acc[4][4] = {};

    for (int k0 = 0; k0 < K; k0 += 64) {
        {
            int r = tid >> 1, co = (tid & 1) * 32;
            const bf16* src = A + (size_t)(m0 + r) * K + k0 + co;
            bf16* dst = sA + r * 72 + co;
            *(uint4*)(dst +  0) = *(const uint4*)(src +  0);
            *(uint4*)(dst +  8) = *(const uint4*)(src +  8);
            *(uint4*)(dst + 16) = *(const uint4*)(src + 16);
            *(uint4*)(dst + 24) = *(const uint4*)(src + 24);
        }
        {
            int r = tid >> 1, co = (tid & 1) * 32;
            const float* src = W + (size_t)(n0 + r) * K + k0 + co;
            bf16* dst = sB + r * 72 + co;
#pragma unroll
            for (int i = 0; i < 32; i += 8) {
                f32x4 v0 = *(const f32x4*)(src + i);
                f32x4 v1 = *(const f32x4*)(src + i + 4);
                bf16x8 o;
                o[0]=(bf16)v0[0]; o[1]=(bf16)v0[1]; o[2]=(bf16)v0[2]; o[3]=(bf16)v0[3];
                o[4]=(bf16)v1[0]; o[5]=(bf16)v1[1]; o[6]=(bf16)v1[2]; o[7]=(bf16)v1[3];
                *(bf16x8*)(dst + i) = o;
            }
        }
        __syncthreads();
#pragma unroll
        for (int kk = 0; kk < 2; kk++) {
            bf16x8 af[4], bfr[4];
#pragma unroll
            for (int mt = 0; mt < 4; mt++)
                af[mt] = *(const bf16x8*)(sA + (wm * 64 + mt * 16 + l15) * 72 + kk * 32 + quad * 8);
#pragma unroll
            for (int nt = 0; nt < 4; nt++)
                bfr[nt] = *(const bf16x8*)(sB + (wn * 64 + nt * 16 + l15) * 72 + kk * 32 + quad * 8);
#pragma unroll
            for (int mt = 0; mt < 4; mt++)
#pragma unroll
                for (int nt = 0; nt < 4; nt++)
                    acc[mt][nt] = __builtin_amdgcn_mfma_f32_16x16x32_bf16(af[mt], bfr[nt], acc[mt][nt], 0, 0, 0);
        }
        __syncthreads();
    }
#pragma unroll
    for (int mt = 0; mt < 4; mt++) {
#pragma unroll
        for (int nt = 0; nt < 4; nt++) {
            int col = n0 + wn * 64 + nt * 16 + l15;
            float bv = bias[col];
            int row0 = m0 + wm * 64 + mt * 16 + quad * 4;
#pragma unroll
            for (int r4 = 0; r4 < 4; r4++) {
                float v = acc[mt][nt][r4] + bv;
                int r = row0 + r4;
                if (out_mode == 3) {
                    int tt = r & (NS - 1), b = r >> 9;
                    int dd = col >> 10, g = (col >> 8) & 3, j = col & 255;
                    ((bf16*)Cout)[(((((size_t)tt * 64 + b) * 2 + dd) * 256 + j) << 2) + g] = (bf16)v;
                } else {
                    ((float*)Cout)[(size_t)r * N + col] = v;
                }
            }
        }
    }
}

// ---------------- Whh int8 pre-pack + per-row scales ----------------
// One wave per weight row (NL*2*1024 rows). Fragment layout for mfma_i32_16x16x64_i8:
// cell (layer,d,w, nt*4+kt): frag-lane q*16+l15r holds row (g*256+w*32+hi*16+l15r),
// bytes k = kt*64 + q*16 + j (j=0..15), nt = g*2+hi.
__global__ void k_prep_i8(const float* __restrict__ Whh0, const float* __restrict__ WhhL,
                          signed char* __restrict__ Wp8, float* __restrict__ scales) {
    int gw = blockIdx.x * 4 + (threadIdx.x >> 6);   // row id < 10240
    int lane = threadIdx.x & 63;
    int row = gw & 1023;
    int d = (gw >> 10) & 1;
    int layer = gw >> 11;
    const float* src = (layer == 0)
        ? (Whh0 + ((size_t)d * 1024 + row) * 256)
        : (WhhL + (((size_t)(layer - 1) * 2 + d) * 1024 + row) * 256);
    f32x4 v = *(const f32x4*)(src + lane * 4);
    float am = fmaxf(fmaxf(fabsf(v[0]), fabsf(v[1])), fmaxf(fabsf(v[2]), fabsf(v[3])));
#pragma unroll
    for (int off = 32; off >= 1; off >>= 1) am = fmaxf(am, __shfl_xor(am, off));
    am = fmaxf(am, 1e-8f);
    float inv = 127.f / am;
    int q0 = (int)__builtin_rintf(v[0] * inv);
    int q1 = (int)__builtin_rintf(v[1] * inv);
    int q2 = (int)__builtin_rintf(v[2] * inv);
    int q3 = (int)__builtin_rintf(v[3] * inv);
    uint32_t packed = (q0 & 255) | ((q1 & 255) << 8) | ((q2 & 255) << 16) | ((q3 & 255) << 24);
    int g = row >> 8, rem = row & 255;
    int w = rem >> 5, hi = (rem >> 4) & 1, l15r = rem & 15;
    int nt = g * 2 + hi;
    int k = lane * 4;
    int kt = k >> 6, q = (k >> 4) & 3, j = k & 15;
    size_t cell = (((size_t)layer * 2 + d) * 8 + w) * 32 + nt * 4 + kt;
    *(uint32_t*)(Wp8 + cell * 1024 + (q * 16 + l15r) * 16 + j) = packed;
    if (lane == 0)
        scales[((size_t)layer * 2 + d) * 1024 + row] = am * (1.f / (127.f * 127.f));
}

// ---------------- LSTM recurrence: int8 register-resident weights, zero streaming ----------------
// grid = 8 blocks x 512 threads; block = (dir d, batch group of 16).
// Whh (i8, per-row scaled) fully register-resident: 8 nt x 4 kt x 16B/lane = 128 VGPR.
// G gate-interleaved [tt][b][d][j][4] -> 8 coalesced 8B loads/thread, no LDS staging.
// h kept in LDS as i8 (scale 127), XOR-swizzled 16B chunks (conflict-free reads).
// One __syncthreads per step.
__global__ __launch_bounds__(512, 2)
void k_lstm_i8(const bf16* __restrict__ G,     // [S][64][2][256][4]
               const signed char* __restrict__ Wp8,  // [2][8][32][1024] for this layer
               const float* __restrict__ sc,   // [2][1024]
               bf16* __restrict__ io_out)      // [64][S][512]
{
    __shared__ signed char hs[2][4096];   // h dbuf: [b=16][256], chunk ^ row swizzle

    const int d  = blockIdx.x & 1;
    const int bg = blockIdx.x >> 1;
    const int tid = threadIdx.x;
    const int w = tid >> 6, lane = tid & 63;
    const int l15 = lane & 15, quad = lane >> 4;
    const int b0g = bg * 16;

    // resident weights: 128 VGPRs
    const signed char* wb = Wp8 + (((size_t)d * 8 + w) * 32) * 1024 + lane * 16;
    v4i Wr[8][4];
#pragma unroll
    for (int nt = 0; nt < 8; nt++)
#pragma unroll
        for (int kt = 0; kt < 4; kt++)
            Wr[nt][kt] = *(const v4i*)(wb + (nt * 4 + kt) * 1024);

    // per-lane combined scales (row scale / 127^2) for the 8 n-tiles
    float scv[8];
#pragma unroll
    for (int nt = 0; nt < 8; nt++)
        scv[nt] = sc[d * 1024 + (nt >> 1) * 256 + w * 32 + (nt & 1) * 16 + l15];

    // precomputed offsets
    int goff[2][4];   // G element offsets (x4-gate units) minus the tt term
    int iooff[2][4];  // io_out offsets minus tt*512
    int hwo[2][4];    // LDS write offsets
#pragma unroll
    for (int hi = 0; hi < 2; hi++)
#pragma unroll
        for (int r = 0; r < 4; r++) {
            int bl = quad * 4 + r;
            int j = w * 32 + hi * 16 + l15;
            goff[hi][r]  = (((bl * 2 + d) * 256 + j) << 2);
            iooff[hi][r] = ((b0g + bl) * NS) * 512 + d * 256 + j;
            hwo[hi][r]   = bl * 256 + (((w * 2 + hi) ^ bl) << 4) + l15;
        }
    int hro[4];
#pragma unroll
    for (int kt = 0; kt < 4; kt++)
        hro[kt] = l15 * 256 + (((kt * 4 + quad) ^ l15) << 4);

    float cst[2][4] = {{0.f,0.f,0.f,0.f},{0.f,0.f,0.f,0.f}};

    for (int t = 0; t < NS; t++) {
        const int tt = d ? (NS - 1 - t) : t;
        const int rb = (t + 1) & 1, wbuf = t & 1;

        // 1. issue G loads first (h-independent, consumed at the end)
        const bf16* gbase = G + (size_t)tt * 131072;
        bf16x4 gv[2][4];
#pragma unroll
        for (int hi = 0; hi < 2; hi++)
#pragma unroll
            for (int r = 0; r < 4; r++)
                gv[hi][r] = *(const bf16x4*)(gbase + goff[hi][r]);

        // 2. MFMA: gates = Whh_i8 . h_i8
        v4i acc[8] = {};
        if (t > 0) {
            v4i af[4];
#pragma unroll
            for (int kt = 0; kt < 4; kt++)
                af[kt] = *(const v4i*)&hs[rb][hro[kt]];
#pragma unroll
            for (int kt = 0; kt < 4; kt++)
#pragma unroll
                for (int nt = 0; nt < 8; nt++)
                    acc[nt] = __builtin_amdgcn_mfma_i32_16x16x64_i8(af[kt], Wr[nt][kt], acc[nt], 0, 0, 0);
        }

        // 3. elementwise gates -> c,h
#pragma unroll
        for (int hi = 0; hi < 2; hi++) {
#pragma unroll
            for (int r = 0; r < 4; r++) {
                bf16x4 g4 = gv[hi][r];
                float pi = (float)acc[0 + hi][r] * scv[0 + hi] + (float)g4[0];
                float pf = (float)acc[2 + hi][r] * scv[2 + hi] + (float)g4[1];
                float pg = (float)acc[4 + hi][r] * scv[4 + hi] + (float)g4[2];
                float po = (float)acc[6 + hi][r] * scv[6 + hi] + (float)g4[3];
                float ig = sigm(pi), fg = sigm(pf), gc = tanh_(pg), og = sigm(po);
                float c = fg * cst[hi][r] + ig * gc;
                cst[hi][r] = c;
                float hh = og * tanh_(c);
                io_out[(size_t)iooff[hi][r] + tt * 512] = (bf16)hh;
                int hq = (int)__builtin_rintf(hh * 127.f);
                hs[wbuf][hwo[hi][r]] = (signed char)hq;
            }
        }
        __syncthreads();   // h(t) visible for step t+1
    }
}

// ---------------- GCN banded adjacency matmul -> bf16 ----------------
__global__ void k_banded(const float* __restrict__ x, const float* __restrict__ mask,
                         bf16* __restrict__ outb) {
    int t  = blockIdx.x * 256 + threadIdx.x;  // < 64*512*64
    int bs = t >> 6;
    int c4 = (t & 63) << 2;
    int s = bs & (NS - 1);
    float m  = mask[bs];
    float mn = (s < NS - 1) ? mask[bs + 1] : 0.f;
    float mp = (s > 0)      ? mask[bs - 1] : 0.f;
    float rs = m * (mp + mn) + 1e-8f;
    float cn = m * mn / rs;
    float cp = m * mp / rs;
    f32x4 vn = {}, vp = {};
    if (s < NS - 1) vn = *(const f32x4*)(x + (size_t)(bs + 1) * NGC + c4);
    if (s > 0)      vp = *(const f32x4*)(x + (size_t)(bs - 1) * NGC + c4);
    bf16x4 o;
#pragma unroll
    for (int i = 0; i < 4; i++) o[i] = (bf16)(cn * vn[i] + cp * vp[i]);
    *(bf16x4*)(outb + (size_t)bs * NGC + c4) = o;
}

// ---------------- GCN residual + layernorm + relu (one wave per row) ----------------
__global__ void k_gcnpost(const float* __restrict__ gemm_out, const float* __restrict__ x,
                          const float* __restrict__ gamma, const float* __restrict__ beta,
                          float* __restrict__ outx) {
    int row  = blockIdx.x * 4 + (threadIdx.x >> 6);
    int lane = threadIdx.x & 63;
    const float* h  = gemm_out + (size_t)row * NGC;
    const float* xr = x + (size_t)row * NGC;
    f32x4 hv = *(const f32x4*)(h + lane * 4);
    f32x4 xv = *(const f32x4*)(xr + lane * 4);
    f32x4 v;
#pragma unroll
    for (int i = 0; i < 4; i++) v[i] = hv[i] + xv[i];
    float sum = v[0] + v[1] + v[2] + v[3];
#pragma unroll
    for (int off = 32; off >= 1; off >>= 1) sum += __shfl_xor(sum, off);
    float mu = sum * (1.f / NGC);
    float sq = 0.f;
    f32x4 dv;
#pragma unroll
    for (int i = 0; i < 4; i++) { dv[i] = v[i] - mu; sq += dv[i] * dv[i]; }
#pragma unroll
    for (int off = 32; off >= 1; off >>= 1) sq += __shfl_xor(sq, off);
    float inv = rsqrtf(sq * (1.f / NGC) + 1e-5f);
    f32x4 o;
#pragma unroll
    for (int i = 0; i < 4; i++) {
        int c = lane * 4 + i;
        float y = dv[i] * inv * gamma[c] + beta[c];
        o[i] = fmaxf(y, 0.f);
    }
    *(f32x4*)(outx + (size_t)row * NGC + lane * 4) = o;
}

// ---------------- masked mean pooling ----------------
__global__ void k_pool_bf16(const bf16* __restrict__ src, const float* __restrict__ mask,
                            float* __restrict__ feat) {  // F = 512
    int b = blockIdx.x, f = threadIdx.x;
    float acc = 0.f, dm = 0.f;
    for (int t = 0; t < NS; t++) {
        float m = mask[b * NS + t];
        acc += m * (float)src[((size_t)b * NS + t) * 512 + f];
        dm += m;
    }
    feat[b * 512 + f] = acc / fmaxf(dm, 1e-8f);
}
__global__ void k_pool_f32(const float* __restrict__ src, const float* __restrict__ mask,
                           float* __restrict__ feat) {  // F = 256
    int b = blockIdx.x, f = threadIdx.x;
    float acc = 0.f, dm = 0.f;
    for (int t = 0; t < NS; t++) {
        float m = mask[b * NS + t];
        acc += m * src[((size_t)b * NS + t) * NGC + f];
        dm += m;
    }
    feat[b * NGC + f] = acc / fmaxf(dm, 1e-8f);
}

// ---------------- fused head ----------------
__global__ __launch_bounds__(512)
void k_head(const float* __restrict__ lfeat, const float* __restrict__ gfeat,
            const float* __restrict__ aux,
            const float* __restrict__ fc1W, const float* __restrict__ fc1b,
            const float* __restrict__ fc2W, const float* __restrict__ fc2b,
            const float* __restrict__ h0W, const float* __restrict__ h0b,
            const float* __restrict__ h1W, const float* __restrict__ h1b,
            float* __restrict__ out) {
    __shared__ float fused[FUSION];
    __shared__ float s1[512];
    __shared__ float s2[256];
    int m = blockIdx.x, tid = threadIdx.x;
    if (tid < 512) fused[tid] = lfeat[m * 512 + tid];
    if (tid < 256) fused[512 + tid] = gfeat[m * 256 + tid];
    if (tid < 6)   fused[768 + tid] = aux[m * 6 + tid];
    __syncthreads();
    {
        float a = fc1b[tid];
        const float* w = fc1W + (size_t)tid * FUSION;
        for (int k = 0; k < FUSION; k++) a += w[k] * fused[k];
        s1[tid] = fmaxf(a, 0.f);
    }
    __syncthreads();
    if (tid < 256) {
        float a = fc2b[tid];
        const float* w = fc2W + (size_t)tid * 512;
        for (int k = 0; k < 512; k++) a += w[k] * s1[k];
        s2[tid] = fmaxf(a, 0.f);
    }
    __syncthreads();
    if (tid < 15) {
        if (tid < 10) {
            float a = h0b[tid];
            const float* w = h0W + (size_t)tid * 256;
            for (int k = 0; k < 256; k++) a += w[k] * s2[k];
            out[m * 10 + tid] = a;
        } else {
            int n = tid - 10;
            float a = h1b[n];
            const float* w = h1W + (size_t)n * 256;
            for (int k = 0; k < 256; k++) a += w[k] * s2[k];
            out[640 + m * 5 + n] = a;
        }
    }
}

// ---------------- host launcher ----------------
extern "C" void kernel_launch(void* const* d_in, const int* in_sizes, int n_in,
                              void* d_out, int out_size, void* d_ws, size_t ws_size,
                              hipStream_t stream) {
    const int*   seq   = (const int*)d_in[0];
    const float* mask  = (const float*)d_in[1];
    const float* aux   = (const float*)d_in[2];
    const float* table = (const float*)d_in[3];
    const float* Wih0  = (const float*)d_in[4];
    const float* Whh0  = (const float*)d_in[5];
    const float* b0    = (const float*)d_in[6];
    const float* WihL  = (const float*)d_in[7];
    const float* WhhL  = (const float*)d_in[8];
    const float* bL    = (const float*)d_in[9];
    const float* gcnW  = (const float*)d_in[10];
    const float* gcnb  = (const float*)d_in[11];
    const float* gcnG  = (const float*)d_in[12];
    const float* gcnBe = (const float*)d_in[13];
    const float* fc1W  = (const float*)d_in[14];
    const float* fc1b  = (const float*)d_in[15];
    const float* fc2W  = (const float*)d_in[16];
    const float* fc2b  = (const float*)d_in[17];
    const float* h0W   = (const float*)d_in[18];
    const float* h0b   = (const float*)d_in[19];
    const float* h1W   = (const float*)d_in[20];
    const float* h1b   = (const float*)d_in[21];
    float* outp = (float*)d_out;

    char* ws = (char*)d_ws;
    const size_t MROWS = (size_t)NB * NS;          // 32768
    float* emb_f32 = (float*)(ws + 0);             // 33.55 MB
    bf16*  emb_b   = (bf16*) (ws + 33554432);      // 16.78 MB (dead after L0 gemm)
    signed char* Wp8 = (signed char*)(ws + 33554432); // 2.62 MB, aliases emb_b
    float* wsc     = (float*)(ws + 36175872);      // 40 KB scales
    bf16*  io0     = (bf16*) (ws + 50331648);      // 33.55 MB
    bf16*  io1     = (bf16*) (ws + 83886080);      // 33.55 MB
    char*  Greg    =          ws + 117440512;      // 128 MiB (G; GCN scratch aliases here)
    bf16*  G       = (bf16*)  Greg;
    float* lfeat   = (float*)(ws + 251658240);     // 128 KB
    float* gfeat   = (float*)(ws + 251789312);     // 64 KB
    // GCN aliases (used before G):
    float* gcnA  = (float*)(Greg + 0);
    float* gcnB_ = (float*)(Greg + 33554432);
    float* ggemm = (float*)(Greg + 67108864);
    bf16*  gtmp  = (bf16*) (Greg + 100663296);
    (void)ws_size; (void)n_in; (void)in_sizes; (void)out_size;

    // embedding
    k_embed<<<dim3(8192), dim3(256), 0, stream>>>(seq, table, emb_f32, emb_b);

    // ---- GCN stack ----
    const float* xcur = emb_f32;
    float* xnxt[3] = {gcnA, gcnB_, gcnA};
    for (int i = 0; i < 3; i++) {
        k_banded<<<dim3(8192), dim3(256), 0, stream>>>(xcur, mask, gtmp);
        k_gemm<<<dim3((MROWS / 128) * (NGC / 128)), dim3(256), 0, stream>>>(
            gtmp, gcnW + (size_t)i * NGC * NGC, gcnb + i * NGC, ggemm,
            (int)MROWS, NGC, NGC, 0);
        k_gcnpost<<<dim3(8192), dim3(256), 0, stream>>>(
            ggemm, xcur, gcnG + i * NGC, gcnBe + i * NGC, xnxt[i]);
        xcur = xnxt[i];
    }
    k_pool_f32<<<dim3(NB), dim3(NGC), 0, stream>>>(xcur, mask, gfeat);

    // ---- BiLSTM stack ----
    const bf16* Xin = emb_b;
    int Kin = NE;
    bf16* ios[2] = {io0, io1};
    for (int l = 0; l < NL; l++) {
        const float* wih  = l ? (WihL + (size_t)(l - 1) * 2 * 1024 * 512) : Wih0;
        const float* bias = l ? (bL + (size_t)(l - 1) * 2048) : b0;
        k_gemm<<<dim3((MROWS / 128) * (2048 / 128)), dim3(256), 0, stream>>>(
            Xin, wih, bias, G, (int)MROWS, 2048, Kin, 3);
        if (l == 0) {
            // emb_b consumed; quantize+pack all layers' Whh to int8 fragment layout
            k_prep_i8<<<dim3(2560), dim3(256), 0, stream>>>(Whh0, WhhL, Wp8, wsc);
        }
        bf16* lio = ios[l & 1];
        k_lstm_i8<<<dim3(8), dim3(512), 0, stream>>>(
            G, Wp8 + (size_t)l * 524288, wsc + (size_t)l * 2048, lio);
        Xin = lio;
        Kin = 512;
    }
    k_pool_bf16<<<dim3(NB), dim3(512), 0, stream>>>(ios[(NL - 1) & 1], mask, lfeat);

    // ---- fused head ----
    k_head<<<dim3(NB), dim3(512), 0, stream>>>(
        lfeat, gfeat, aux, fc1W, fc1b, fc2W, fc2b, h0W, h0b, h1W, h1b, outp);
}

// Round 4
// 4612.500 us; speedup vs baseline: 6.9529x; 2.3226x over previous
//
#include <hip/hip_runtime.h>
#include <stdint.h>
#include <stddef.h>

// ---------------- types ----------------
typedef __bf16 bf16;
typedef __bf16 bf16x8 __attribute__((ext_vector_type(8)));
typedef __bf16 bf16x4 __attribute__((ext_vector_type(4)));
typedef float  f32x4  __attribute__((ext_vector_type(4)));
typedef int    v4i    __attribute__((ext_vector_type(4)));

// ---------------- problem constants ----------------
#define NB   64      // batch
#define NS   512     // seq len
#define NE   256     // embed dim
#define NH   256     // lstm hidden
#define NL   5       // lstm layers
#define NGC  256     // gcn hidden
#define FUSION 774   // 2H + GC + 6

__device__ __forceinline__ float sigm(float x) {
    return __fdividef(1.f, 1.f + __expf(-x));
}
__device__ __forceinline__ float tanh_(float x) {
    return __fdividef(2.f, 1.f + __expf(-2.f * x)) - 1.f;
}

// ---------------- embedding gather (f32 + bf16 copies) ----------------
__global__ void k_embed(const int* __restrict__ seq, const float* __restrict__ table,
                        float* __restrict__ ef, bf16* __restrict__ eb) {
    int t  = blockIdx.x * 256 + threadIdx.x;  // < 64*512*64
    int bs = t >> 6;
    int c4 = (t & 63) << 2;
    int row = seq[bs];
    f32x4 v = *(const f32x4*)(table + (size_t)row * NE + c4);
    *(f32x4*)(ef + (size_t)bs * NE + c4) = v;
    bf16x4 o;
    o[0] = (bf16)v[0]; o[1] = (bf16)v[1]; o[2] = (bf16)v[2]; o[3] = (bf16)v[3];
    *(bf16x4*)(eb + (size_t)bs * NE + c4) = o;
}

// ---------------- generic bf16 MFMA GEMM: C[M,N] = A[M,K](bf16) * W[N,K](f32)^T + bias ----------------
// out_mode: 0 = f32 [M,N]; 3 = bf16 gate-interleaved [tt][b][d][j][g] with
//           m = b*NS+tt, col = d*1024 + g*256 + j
__global__ __launch_bounds__(256, 2)
void k_gemm(const bf16* __restrict__ A, const float* __restrict__ W,
            const float* __restrict__ bias, void* __restrict__ Cout,
            int M, int N, int K, int out_mode) {
    __shared__ bf16 sA[128 * 72];
    __shared__ bf16 sB[128 * 72];
    const int mblk = M >> 7;
    int bm = blockIdx.x % mblk;
    int bn = blockIdx.x / mblk;
    int m0 = bm << 7, n0 = bn << 7;
    int tid  = threadIdx.x;
    int wave = tid >> 6, lane = tid & 63;
    int wm = wave >> 1, wn = wave & 1;
    int l15 = lane & 15, quad = lane >> 4;

    f32x4 acc[4][4] = {};

    for (int k0 = 0; k0 < K; k0 += 64) {
        {
            int r = tid >> 1, co = (tid & 1) * 32;
            const bf16* src = A + (size_t)(m0 + r) * K + k0 + co;
            bf16* dst = sA + r * 72 + co;
            *(uint4*)(dst +  0) = *(const uint4*)(src +  0);
            *(uint4*)(dst +  8) = *(const uint4*)(src +  8);
            *(uint4*)(dst + 16) = *(const uint4*)(src + 16);
            *(uint4*)(dst + 24) = *(const uint4*)(src + 24);
        }
        {
            int r = tid >> 1, co = (tid & 1) * 32;
            const float* src = W + (size_t)(n0 + r) * K + k0 + co;
            bf16* dst = sB + r * 72 + co;
#pragma unroll
            for (int i = 0; i < 32; i += 8) {
                f32x4 v0 = *(const f32x4*)(src + i);
                f32x4 v1 = *(const f32x4*)(src + i + 4);
                bf16x8 o;
                o[0]=(bf16)v0[0]; o[1]=(bf16)v0[1]; o[2]=(bf16)v0[2]; o[3]=(bf16)v0[3];
                o[4]=(bf16)v1[0]; o[5]=(bf16)v1[1]; o[6]=(bf16)v1[2]; o[7]=(bf16)v1[3];
                *(bf16x8*)(dst + i) = o;
            }
        }
        __syncthreads();
#pragma unroll
        for (int kk = 0; kk < 2; kk++) {
            bf16x8 af[4], bfr[4];
#pragma unroll
            for (int mt = 0; mt < 4; mt++)
                af[mt] = *(const bf16x8*)(sA + (wm * 64 + mt * 16 + l15) * 72 + kk * 32 + quad * 8);
#pragma unroll
            for (int nt = 0; nt < 4; nt++)
                bfr[nt] = *(const bf16x8*)(sB + (wn * 64 + nt * 16 + l15) * 72 + kk * 32 + quad * 8);
#pragma unroll
            for (int mt = 0; mt < 4; mt++)
#pragma unroll
                for (int nt = 0; nt < 4; nt++)
                    acc[mt][nt] = __builtin_amdgcn_mfma_f32_16x16x32_bf16(af[mt], bfr[nt], acc[mt][nt], 0, 0, 0);
        }
        __syncthreads();
    }
#pragma unroll
    for (int mt = 0; mt < 4; mt++) {
#pragma unroll
        for (int nt = 0; nt < 4; nt++) {
            int col = n0 + wn * 64 + nt * 16 + l15;
            float bv = bias[col];
            int row0 = m0 + wm * 64 + mt * 16 + quad * 4;
#pragma unroll
            for (int r4 = 0; r4 < 4; r4++) {
                float v = acc[mt][nt][r4] + bv;
                int r = row0 + r4;
                if (out_mode == 3) {
                    int tt = r & (NS - 1), b = r >> 9;
                    int dd = col >> 10, g = (col >> 8) & 3, j = col & 255;
                    ((bf16*)Cout)[(((((size_t)tt * 64 + b) * 2 + dd) * 256 + j) << 2) + g] = (bf16)v;
                } else {
                    ((float*)Cout)[(size_t)r * N + col] = v;
                }
            }
        }
    }
}

// ---------------- Whh int8 pre-pack + per-row scales ----------------
// One wave per weight row (NL*2*1024 rows). Fragment layout for mfma_i32_16x16x64_i8:
// cell (layer,d,w, nt*4+kt): frag-lane q*16+l15r holds row (g*256+w*32+hi*16+l15r),
// bytes k = kt*64 + q*16 + j (j=0..15), nt = g*2+hi.
__global__ void k_prep_i8(const float* __restrict__ Whh0, const float* __restrict__ WhhL,
                          signed char* __restrict__ Wp8, float* __restrict__ scales) {
    int gw = blockIdx.x * 4 + (threadIdx.x >> 6);   // row id < 10240
    int lane = threadIdx.x & 63;
    int row = gw & 1023;
    int d = (gw >> 10) & 1;
    int layer = gw >> 11;
    const float* src = (layer == 0)
        ? (Whh0 + ((size_t)d * 1024 + row) * 256)
        : (WhhL + (((size_t)(layer - 1) * 2 + d) * 1024 + row) * 256);
    f32x4 v = *(const f32x4*)(src + lane * 4);
    float am = fmaxf(fmaxf(fabsf(v[0]), fabsf(v[1])), fmaxf(fabsf(v[2]), fabsf(v[3])));
#pragma unroll
    for (int off = 32; off >= 1; off >>= 1) am = fmaxf(am, __shfl_xor(am, off));
    am = fmaxf(am, 1e-8f);
    float inv = 127.f / am;
    int q0 = (int)__builtin_rintf(v[0] * inv);
    int q1 = (int)__builtin_rintf(v[1] * inv);
    int q2 = (int)__builtin_rintf(v[2] * inv);
    int q3 = (int)__builtin_rintf(v[3] * inv);
    uint32_t packed = (q0 & 255) | ((q1 & 255) << 8) | ((q2 & 255) << 16) | ((q3 & 255) << 24);
    int g = row >> 8, rem = row & 255;
    int w = rem >> 5, hi = (rem >> 4) & 1, l15r = rem & 15;
    int nt = g * 2 + hi;
    int k = lane * 4;
    int kt = k >> 6, q = (k >> 4) & 3, j = k & 15;
    size_t cell = (((size_t)layer * 2 + d) * 8 + w) * 32 + nt * 4 + kt;
    *(uint32_t*)(Wp8 + cell * 1024 + (q * 16 + l15r) * 16 + j) = packed;
    if (lane == 0)
        scales[((size_t)layer * 2 + d) * 1024 + row] = am * (1.f / (127.f * 127.f));
}

// ---------------- LSTM recurrence: 32 blocks, 4 batches/block, K-quarter row remap ----------------
// grid = 32 blocks x 512 threads; block = (dir d, batch group of 4).
// A-row m = b*4 + rr (rr = K-quarter). Lane l15 loads ONE 16B h chunk at LDS
// addr l15*64+quad*16 (contiguous 1KB/wave, conflict-free); MFMA round kt uses
// A = ((l15&3)==kt) ? chunk : 0. acc[nt][r] = K-quarter-r partial for batch=quad
// -> gate preact = lane-local int sum of 4 regs. 2 gate-cells/lane, balanced.
// G loads software-pipelined one step ahead.
__global__ __launch_bounds__(512, 2)
void k_lstm_i8(const bf16* __restrict__ G,     // [S][64][2][256][4]
               const signed char* __restrict__ Wp8,  // [2][8][32][1024] for this layer
               const float* __restrict__ sc,   // [2][1024]
               bf16* __restrict__ io_out)      // [64][S][512]
{
    __shared__ signed char hs[2][1024];   // h dbuf: [b_local=4][256]

    const int d  = blockIdx.x & 1;
    const int bg = blockIdx.x >> 1;       // 0..15
    const int tid = threadIdx.x;
    const int w = tid >> 6, lane = tid & 63;
    const int l15 = lane & 15, quad = lane >> 4;
    const int b = bg * 4 + quad;          // global batch handled by this lane

    // resident weights: 128 VGPRs (same packed layout as R3)
    const signed char* wb = Wp8 + (((size_t)d * 8 + w) * 32) * 1024 + lane * 16;
    v4i Wr[8][4];
#pragma unroll
    for (int nt = 0; nt < 8; nt++)
#pragma unroll
        for (int kt = 0; kt < 4; kt++)
            Wr[nt][kt] = *(const v4i*)(wb + (nt * 4 + kt) * 1024);

    // per-lane combined scales (row scale / 127^2) for the 8 n-tiles
    float scv[8];
#pragma unroll
    for (int nt = 0; nt < 8; nt++)
        scv[nt] = sc[d * 1024 + (nt >> 1) * 256 + w * 32 + (nt & 1) * 16 + l15];

    // per-lane offsets
    int goffs[2], iobs[2], hwr[2];
#pragma unroll
    for (int hi = 0; hi < 2; hi++) {
        int j = w * 32 + hi * 16 + l15;
        goffs[hi] = ((b * 2 + d) * 256 + j) * 4;       // + tt*131072
        iobs[hi]  = b * NS * 512 + d * 256 + j;        // + tt*512
        hwr[hi]   = quad * 256 + j;                     // LDS write
    }
    const int hrd = l15 * 64 + quad * 16;               // LDS read (16B chunk)

    float cst[2] = {0.f, 0.f};

    // pipeline: G for step 0
    int tt = d ? (NS - 1) : 0;
    bf16x4 gv[2];
#pragma unroll
    for (int hi = 0; hi < 2; hi++)
        gv[hi] = *(const bf16x4*)(G + (size_t)tt * 131072 + goffs[hi]);

    for (int t = 0; t < NS; t++) {
        const int rb = (t + 1) & 1, wbuf = t & 1;
        const int tt_n = d ? (NS - 2 - t) : (t + 1);

        // prefetch next step's G (independent of everything this step)
        bf16x4 gn[2];
        if (t < NS - 1) {
#pragma unroll
            for (int hi = 0; hi < 2; hi++)
                gn[hi] = *(const bf16x4*)(G + (size_t)tt_n * 131072 + goffs[hi]);
        }

        // MFMA: gates = Whh_i8 . h_i8 with K-quarter row remap
        v4i acc[8] = {};
        if (t > 0) {
            v4i chunk = *(const v4i*)&hs[rb][hrd];
            const int rr = l15 & 3;
#pragma unroll
            for (int kt = 0; kt < 4; kt++) {
                v4i a;
                a[0] = (rr == kt) ? chunk[0] : 0;
                a[1] = (rr == kt) ? chunk[1] : 0;
                a[2] = (rr == kt) ? chunk[2] : 0;
                a[3] = (rr == kt) ? chunk[3] : 0;
#pragma unroll
                for (int nt = 0; nt < 8; nt++)
                    acc[nt] = __builtin_amdgcn_mfma_i32_16x16x64_i8(a, Wr[nt][kt], acc[nt], 0, 0, 0);
            }
        }

        // elementwise: 2 cells/lane (batch=quad, j = w*32+hi*16+l15)
#pragma unroll
        for (int hi = 0; hi < 2; hi++) {
            bf16x4 g4 = gv[hi];
            int si = acc[0 + hi][0] + acc[0 + hi][1] + acc[0 + hi][2] + acc[0 + hi][3];
            int sf = acc[2 + hi][0] + acc[2 + hi][1] + acc[2 + hi][2] + acc[2 + hi][3];
            int sg = acc[4 + hi][0] + acc[4 + hi][1] + acc[4 + hi][2] + acc[4 + hi][3];
            int so = acc[6 + hi][0] + acc[6 + hi][1] + acc[6 + hi][2] + acc[6 + hi][3];
            float pi = (float)si * scv[0 + hi] + (float)g4[0];
            float pf = (float)sf * scv[2 + hi] + (float)g4[1];
            float pg = (float)sg * scv[4 + hi] + (float)g4[2];
            float po = (float)so * scv[6 + hi] + (float)g4[3];
            float ig = sigm(pi), fg = sigm(pf), gc = tanh_(pg), og = sigm(po);
            float c = fg * cst[hi] + ig * gc;
            cst[hi] = c;
            float hh = og * tanh_(c);
            io_out[(size_t)iobs[hi] + tt * 512] = (bf16)hh;
            int hq = (int)__builtin_rintf(hh * 127.f);
            hs[wbuf][hwr[hi]] = (signed char)hq;
        }
        gv[0] = gn[0]; gv[1] = gn[1];
        tt = tt_n;
        __syncthreads();   // h(t) visible for step t+1
    }
}

// ---------------- GCN banded adjacency matmul -> bf16 ----------------
__global__ void k_banded(const float* __restrict__ x, const float* __restrict__ mask,
                         bf16* __restrict__ outb) {
    int t  = blockIdx.x * 256 + threadIdx.x;  // < 64*512*64
    int bs = t >> 6;
    int c4 = (t & 63) << 2;
    int s = bs & (NS - 1);
    float m  = mask[bs];
    float mn = (s < NS - 1) ? mask[bs + 1] : 0.f;
    float mp = (s > 0)      ? mask[bs - 1] : 0.f;
    float rs = m * (mp + mn) + 1e-8f;
    float cn = m * mn / rs;
    float cp = m * mp / rs;
    f32x4 vn = {}, vp = {};
    if (s < NS - 1) vn = *(const f32x4*)(x + (size_t)(bs + 1) * NGC + c4);
    if (s > 0)      vp = *(const f32x4*)(x + (size_t)(bs - 1) * NGC + c4);
    bf16x4 o;
#pragma unroll
    for (int i = 0; i < 4; i++) o[i] = (bf16)(cn * vn[i] + cp * vp[i]);
    *(bf16x4*)(outb + (size_t)bs * NGC + c4) = o;
}

// ---------------- GCN residual + layernorm + relu (one wave per row) ----------------
__global__ void k_gcnpost(const float* __restrict__ gemm_out, const float* __restrict__ x,
                          const float* __restrict__ gamma, const float* __restrict__ beta,
                          float* __restrict__ outx) {
    int row  = blockIdx.x * 4 + (threadIdx.x >> 6);
    int lane = threadIdx.x & 63;
    const float* h  = gemm_out + (size_t)row * NGC;
    const float* xr = x + (size_t)row * NGC;
    f32x4 hv = *(const f32x4*)(h + lane * 4);
    f32x4 xv = *(const f32x4*)(xr + lane * 4);
    f32x4 v;
#pragma unroll
    for (int i = 0; i < 4; i++) v[i] = hv[i] + xv[i];
    float sum = v[0] + v[1] + v[2] + v[3];
#pragma unroll
    for (int off = 32; off >= 1; off >>= 1) sum += __shfl_xor(sum, off);
    float mu = sum * (1.f / NGC);
    float sq = 0.f;
    f32x4 dv;
#pragma unroll
    for (int i = 0; i < 4; i++) { dv[i] = v[i] - mu; sq += dv[i] * dv[i]; }
#pragma unroll
    for (int off = 32; off >= 1; off >>= 1) sq += __shfl_xor(sq, off);
    float inv = rsqrtf(sq * (1.f / NGC) + 1e-5f);
    f32x4 o;
#pragma unroll
    for (int i = 0; i < 4; i++) {
        int c = lane * 4 + i;
        float y = dv[i] * inv * gamma[c] + beta[c];
        o[i] = fmaxf(y, 0.f);
    }
    *(f32x4*)(outx + (size_t)row * NGC + lane * 4) = o;
}

// ---------------- masked mean pooling ----------------
__global__ void k_pool_bf16(const bf16* __restrict__ src, const float* __restrict__ mask,
                            float* __restrict__ feat) {  // F = 512
    int b = blockIdx.x, f = threadIdx.x;
    float acc = 0.f, dm = 0.f;
    for (int t = 0; t < NS; t++) {
        float m = mask[b * NS + t];
        acc += m * (float)src[((size_t)b * NS + t) * 512 + f];
        dm += m;
    }
    feat[b * 512 + f] = acc / fmaxf(dm, 1e-8f);
}
__global__ void k_pool_f32(const float* __restrict__ src, const float* __restrict__ mask,
                           float* __restrict__ feat) {  // F = 256
    int b = blockIdx.x, f = threadIdx.x;
    float acc = 0.f, dm = 0.f;
    for (int t = 0; t < NS; t++) {
        float m = mask[b * NS + t];
        acc += m * src[((size_t)b * NS + t) * NGC + f];
        dm += m;
    }
    feat[b * NGC + f] = acc / fmaxf(dm, 1e-8f);
}

// ---------------- fused head ----------------
__global__ __launch_bounds__(512)
void k_head(const float* __restrict__ lfeat, const float* __restrict__ gfeat,
            const float* __restrict__ aux,
            const float* __restrict__ fc1W, const float* __restrict__ fc1b,
            const float* __restrict__ fc2W, const float* __restrict__ fc2b,
            const float* __restrict__ h0W, const float* __restrict__ h0b,
            const float* __restrict__ h1W, const float* __restrict__ h1b,
            float* __restrict__ out) {
    __shared__ float fused[FUSION];
    __shared__ float s1[512];
    __shared__ float s2[256];
    int m = blockIdx.x, tid = threadIdx.x;
    if (tid < 512) fused[tid] = lfeat[m * 512 + tid];
    if (tid < 256) fused[512 + tid] = gfeat[m * 256 + tid];
    if (tid < 6)   fused[768 + tid] = aux[m * 6 + tid];
    __syncthreads();
    {
        float a = fc1b[tid];
        const float* w = fc1W + (size_t)tid * FUSION;
        for (int k = 0; k < FUSION; k++) a += w[k] * fused[k];
        s1[tid] = fmaxf(a, 0.f);
    }
    __syncthreads();
    if (tid < 256) {
        float a = fc2b[tid];
        const float* w = fc2W + (size_t)tid * 512;
        for (int k = 0; k < 512; k++) a += w[k] * s1[k];
        s2[tid] = fmaxf(a, 0.f);
    }
    __syncthreads();
    if (tid < 15) {
        if (tid < 10) {
            float a = h0b[tid];
            const float* w = h0W + (size_t)tid * 256;
            for (int k = 0; k < 256; k++) a += w[k] * s2[k];
            out[m * 10 + tid] = a;
        } else {
            int n = tid - 10;
            float a = h1b[n];
            const float* w = h1W + (size_t)n * 256;
            for (int k = 0; k < 256; k++) a += w[k] * s2[k];
            out[640 + m * 5 + n] = a;
        }
    }
}

// ---------------- host launcher ----------------
extern "C" void kernel_launch(void* const* d_in, const int* in_sizes, int n_in,
                              void* d_out, int out_size, void* d_ws, size_t ws_size,
                              hipStream_t stream) {
    const int*   seq   = (const int*)d_in[0];
    const float* mask  = (const float*)d_in[1];
    const float* aux   = (const float*)d_in[2];
    const float* table = (const float*)d_in[3];
    const float* Wih0  = (const float*)d_in[4];
    const float* Whh0  = (const float*)d_in[5];
    const float* b0    = (const float*)d_in[6];
    const float* WihL  = (const float*)d_in[7];
    const float* WhhL  = (const float*)d_in[8];
    const float* bL    = (const float*)d_in[9];
    const float* gcnW  = (const float*)d_in[10];
    const float* gcnb  = (const float*)d_in[11];
    const float* gcnG  = (const float*)d_in[12];
    const float* gcnBe = (const float*)d_in[13];
    const float* fc1W  = (const float*)d_in[14];
    const float* fc1b  = (const float*)d_in[15];
    const float* fc2W  = (const float*)d_in[16];
    const float* fc2b  = (const float*)d_in[17];
    const float* h0W   = (const float*)d_in[18];
    const float* h0b   = (const float*)d_in[19];
    const float* h1W   = (const float*)d_in[20];
    const float* h1b   = (const float*)d_in[21];
    float* outp = (float*)d_out;

    char* ws = (char*)d_ws;
    const size_t MROWS = (size_t)NB * NS;          // 32768
    float* emb_f32 = (float*)(ws + 0);             // 33.55 MB
    bf16*  emb_b   = (bf16*) (ws + 33554432);      // 16.78 MB (dead after L0 gemm)
    signed char* Wp8 = (signed char*)(ws + 33554432); // 2.62 MB, aliases emb_b
    float* wsc     = (float*)(ws + 36175872);      // 40 KB scales
    bf16*  io0     = (bf16*) (ws + 50331648);      // 33.55 MB
    bf16*  io1     = (bf16*) (ws + 83886080);      // 33.55 MB
    char*  Greg    =          ws + 117440512;      // 128 MiB (G; GCN scratch aliases here)
    bf16*  G       = (bf16*)  Greg;
    float* lfeat   = (float*)(ws + 251658240);     // 128 KB
    float* gfeat   = (float*)(ws + 251789312);     // 64 KB
    // GCN aliases (used before G):
    float* gcnA  = (float*)(Greg + 0);
    float* gcnB_ = (float*)(Greg + 33554432);
    float* ggemm = (float*)(Greg + 67108864);
    bf16*  gtmp  = (bf16*) (Greg + 100663296);
    (void)ws_size; (void)n_in; (void)in_sizes; (void)out_size;

    // embedding
    k_embed<<<dim3(8192), dim3(256), 0, stream>>>(seq, table, emb_f32, emb_b);

    // ---- GCN stack ----
    const float* xcur = emb_f32;
    float* xnxt[3] = {gcnA, gcnB_, gcnA};
    for (int i = 0; i < 3; i++) {
        k_banded<<<dim3(8192), dim3(256), 0, stream>>>(xcur, mask, gtmp);
        k_gemm<<<dim3((MROWS / 128) * (NGC / 128)), dim3(256), 0, stream>>>(
            gtmp, gcnW + (size_t)i * NGC * NGC, gcnb + i * NGC, ggemm,
            (int)MROWS, NGC, NGC, 0);
        k_gcnpost<<<dim3(8192), dim3(256), 0, stream>>>(
            ggemm, xcur, gcnG + i * NGC, gcnBe + i * NGC, xnxt[i]);
        xcur = xnxt[i];
    }
    k_pool_f32<<<dim3(NB), dim3(NGC), 0, stream>>>(xcur, mask, gfeat);

    // ---- BiLSTM stack ----
    const bf16* Xin = emb_b;
    int Kin = NE;
    bf16* ios[2] = {io0, io1};
    for (int l = 0; l < NL; l++) {
        const float* wih  = l ? (WihL + (size_t)(l - 1) * 2 * 1024 * 512) : Wih0;
        const float* bias = l ? (bL + (size_t)(l - 1) * 2048) : b0;
        k_gemm<<<dim3((MROWS / 128) * (2048 / 128)), dim3(256), 0, stream>>>(
            Xin, wih, bias, G, (int)MROWS, 2048, Kin, 3);
        if (l == 0) {
            // emb_b consumed; quantize+pack all layers' Whh to int8 fragment layout
            k_prep_i8<<<dim3(2560), dim3(256), 0, stream>>>(Whh0, WhhL, Wp8, wsc);
        }
        bf16* lio = ios[l & 1];
        k_lstm_i8<<<dim3(32), dim3(512), 0, stream>>>(
            G, Wp8 + (size_t)l * 524288, wsc + (size_t)l * 2048, lio);
        Xin = lio;
        Kin = 512;
    }
    k_pool_bf16<<<dim3(NB), dim3(512), 0, stream>>>(ios[(NL - 1) & 1], mask, lfeat);

    // ---- fused head ----
    k_head<<<dim3(NB), dim3(512), 0, stream>>>(
        lfeat, gfeat, aux, fc1W, fc1b, fc2W, fc2b, h0W, h0b, h1W, h1b, outp);
}

// Round 5
// 4345.630 us; speedup vs baseline: 7.3799x; 1.0614x over previous
//
#include <hip/hip_runtime.h>
#include <stdint.h>
#include <stddef.h>

// ---------------- types ----------------
typedef __bf16 bf16;
typedef __bf16 bf16x8 __attribute__((ext_vector_type(8)));
typedef __bf16 bf16x4 __attribute__((ext_vector_type(4)));
typedef float  f32x4  __attribute__((ext_vector_type(4)));
typedef int    v4i    __attribute__((ext_vector_type(4)));

// ---------------- problem constants ----------------
#define NB   64      // batch
#define NS   512     // seq len
#define NE   256     // embed dim
#define NH   256     // lstm hidden
#define NL   5       // lstm layers
#define NGC  256     // gcn hidden
#define FUSION 774   // 2H + GC + 6

__device__ __forceinline__ float sigm(float x) {
    return __fdividef(1.f, 1.f + __expf(-x));
}
__device__ __forceinline__ float tanh_(float x) {
    return __fdividef(2.f, 1.f + __expf(-2.f * x)) - 1.f;
}

// ---------------- embedding gather (f32 + bf16 copies) ----------------
__global__ void k_embed(const int* __restrict__ seq, const float* __restrict__ table,
                        float* __restrict__ ef, bf16* __restrict__ eb) {
    int t  = blockIdx.x * 256 + threadIdx.x;  // < 64*512*64
    int bs = t >> 6;
    int c4 = (t & 63) << 2;
    int row = seq[bs];
    f32x4 v = *(const f32x4*)(table + (size_t)row * NE + c4);
    *(f32x4*)(ef + (size_t)bs * NE + c4) = v;
    bf16x4 o;
    o[0] = (bf16)v[0]; o[1] = (bf16)v[1]; o[2] = (bf16)v[2]; o[3] = (bf16)v[3];
    *(bf16x4*)(eb + (size_t)bs * NE + c4) = o;
}

// ---------------- generic bf16 MFMA GEMM: C[M,N] = A[M,K](bf16) * W[N,K](f32)^T + bias ----------------
// out_mode: 0 = f32 [M,N]; 3 = bf16 gate-interleaved [tt][b][d][j][g] with
//           m = b*NS+tt, col = d*1024 + g*256 + j
__global__ __launch_bounds__(256, 2)
void k_gemm(const bf16* __restrict__ A, const float* __restrict__ W,
            const float* __restrict__ bias, void* __restrict__ Cout,
            int M, int N, int K, int out_mode) {
    __shared__ bf16 sA[128 * 72];
    __shared__ bf16 sB[128 * 72];
    const int mblk = M >> 7;
    int bm = blockIdx.x % mblk;
    int bn = blockIdx.x / mblk;
    int m0 = bm << 7, n0 = bn << 7;
    int tid  = threadIdx.x;
    int wave = tid >> 6, lane = tid & 63;
    int wm = wave >> 1, wn = wave & 1;
    int l15 = lane & 15, quad = lane >> 4;

    f32x4 acc[4][4] = {};

    for (int k0 = 0; k0 < K; k0 += 64) {
        {
            int r = tid >> 1, co = (tid & 1) * 32;
            const bf16* src = A + (size_t)(m0 + r) * K + k0 + co;
            bf16* dst = sA + r * 72 + co;
            *(uint4*)(dst +  0) = *(const uint4*)(src +  0);
            *(uint4*)(dst +  8) = *(const uint4*)(src +  8);
            *(uint4*)(dst + 16) = *(const uint4*)(src + 16);
            *(uint4*)(dst + 24) = *(const uint4*)(src + 24);
        }
        {
            int r = tid >> 1, co = (tid & 1) * 32;
            const float* src = W + (size_t)(n0 + r) * K + k0 + co;
            bf16* dst = sB + r * 72 + co;
#pragma unroll
            for (int i = 0; i < 32; i += 8) {
                f32x4 v0 = *(const f32x4*)(src + i);
                f32x4 v1 = *(const f32x4*)(src + i + 4);
                bf16x8 o;
                o[0]=(bf16)v0[0]; o[1]=(bf16)v0[1]; o[2]=(bf16)v0[2]; o[3]=(bf16)v0[3];
                o[4]=(bf16)v1[0]; o[5]=(bf16)v1[1]; o[6]=(bf16)v1[2]; o[7]=(bf16)v1[3];
                *(bf16x8*)(dst + i) = o;
            }
        }
        __syncthreads();
#pragma unroll
        for (int kk = 0; kk < 2; kk++) {
            bf16x8 af[4], bfr[4];
#pragma unroll
            for (int mt = 0; mt < 4; mt++)
                af[mt] = *(const bf16x8*)(sA + (wm * 64 + mt * 16 + l15) * 72 + kk * 32 + quad * 8);
#pragma unroll
            for (int nt = 0; nt < 4; nt++)
                bfr[nt] = *(const bf16x8*)(sB + (wn * 64 + nt * 16 + l15) * 72 + kk * 32 + quad * 8);
#pragma unroll
            for (int mt = 0; mt < 4; mt++)
#pragma unroll
                for (int nt = 0; nt < 4; nt++)
                    acc[mt][nt] = __builtin_amdgcn_mfma_f32_16x16x32_bf16(af[mt], bfr[nt], acc[mt][nt], 0, 0, 0);
        }
        __syncthreads();
    }
#pragma unroll
    for (int mt = 0; mt < 4; mt++) {
#pragma unroll
        for (int nt = 0; nt < 4; nt++) {
            int col = n0 + wn * 64 + nt * 16 + l15;
            float bv = bias[col];
            int row0 = m0 + wm * 64 + mt * 16 + quad * 4;
#pragma unroll
            for (int r4 = 0; r4 < 4; r4++) {
                float v = acc[mt][nt][r4] + bv;
                int r = row0 + r4;
                if (out_mode == 3) {
                    int tt = r & (NS - 1), b = r >> 9;
                    int dd = col >> 10, g = (col >> 8) & 3, j = col & 255;
                    ((bf16*)Cout)[(((((size_t)tt * 64 + b) * 2 + dd) * 256 + j) << 2) + g] = (bf16)v;
                } else {
                    ((float*)Cout)[(size_t)r * N + col] = v;
                }
            }
        }
    }
}

// ---------------- Whh int8 pre-pack + per-row scales ----------------
// One wave per weight row (NL*2*1024 rows). Fragment layout for mfma_i32_16x16x64_i8,
// cell index fi = (w*4 + g)*4 + kt  (w = j-slice of 16, g = gate, kt = K-window of 64):
// frag-lane q*16+l15r holds row (g*256 + w*16 + l15r), bytes k = kt*64 + q*16 + j'.
__global__ void k_prep_i8(const float* __restrict__ Whh0, const float* __restrict__ WhhL,
                          signed char* __restrict__ Wp8, float* __restrict__ scales) {
    int gw = blockIdx.x * 4 + (threadIdx.x >> 6);   // row id < 10240
    int lane = threadIdx.x & 63;
    int row = gw & 1023;
    int d = (gw >> 10) & 1;
    int layer = gw >> 11;
    const float* src = (layer == 0)
        ? (Whh0 + ((size_t)d * 1024 + row) * 256)
        : (WhhL + (((size_t)(layer - 1) * 2 + d) * 1024 + row) * 256);
    f32x4 v = *(const f32x4*)(src + lane * 4);
    float am = fmaxf(fmaxf(fabsf(v[0]), fabsf(v[1])), fmaxf(fabsf(v[2]), fabsf(v[3])));
#pragma unroll
    for (int off = 32; off >= 1; off >>= 1) am = fmaxf(am, __shfl_xor(am, off));
    am = fmaxf(am, 1e-8f);
    float inv = 127.f / am;
    int q0 = (int)__builtin_rintf(v[0] * inv);
    int q1 = (int)__builtin_rintf(v[1] * inv);
    int q2 = (int)__builtin_rintf(v[2] * inv);
    int q3 = (int)__builtin_rintf(v[3] * inv);
    uint32_t packed = (q0 & 255) | ((q1 & 255) << 8) | ((q2 & 255) << 16) | ((q3 & 255) << 24);
    int g = row >> 8, rem = row & 255;
    int w = rem >> 4, l15r = rem & 15;
    int k = lane * 4;
    int kt = k >> 6, q = (k >> 4) & 3, j = k & 15;
    size_t cell = ((size_t)layer * 2 + d) * 256 + (w * 4 + g) * 4 + kt;
    *(uint32_t*)(Wp8 + cell * 1024 + (q * 16 + l15r) * 16 + j) = packed;
    if (lane == 0)
        scales[((size_t)layer * 2 + d) * 1024 + row] = am * (1.f / (127.f * 127.f));
}

// ---------------- LSTM recurrence: 32 blocks x 1024 threads, truly register-resident i8 weights ----------------
// block = (dir d, batch group of 4); wave w owns j-slice w*16..w*16+15 -> only
// 4 nt x 4 kt = 16 MFMAs and 64 weight VGPRs per wave (fits the 128-VGPR cap of a
// 1024-thread block -> compiler keeps weights resident, no L2 restream).
// K-quarter row remap as R4: A-row m = b*4 + rr; acc[g][r] = K-quarter-r partial for
// batch=quad -> gate preact = lane-local int sum; exactly 1 gate-cell per lane.
__global__ __launch_bounds__(1024)
void k_lstm_i8(const bf16* __restrict__ G,     // [S][64][2][256][4]
               const signed char* __restrict__ Wp8,  // [2][256][1024] for this layer
               const float* __restrict__ sc,   // [2][1024]
               bf16* __restrict__ io_out)      // [64][S][512]
{
    __shared__ signed char hs[2][1024];   // h dbuf: [b_local=4][256]

    const int d  = blockIdx.x & 1;
    const int bg = blockIdx.x >> 1;       // 0..15
    const int tid = threadIdx.x;
    const int w = tid >> 6, lane = tid & 63;
    const int l15 = lane & 15, quad = lane >> 4;
    const int b = bg * 4 + quad;          // global batch handled by this lane
    const int j = w * 16 + l15;           // hidden index handled by this lane

    // resident weights: 4 gates x 4 K-windows x 16B = 64 VGPRs
    const signed char* wb = Wp8 + ((size_t)d * 256 + w * 16) * 1024 + lane * 16;
    v4i Wr[4][4];
#pragma unroll
    for (int g = 0; g < 4; g++)
#pragma unroll
        for (int kt = 0; kt < 4; kt++)
            Wr[g][kt] = *(const v4i*)(wb + (g * 4 + kt) * 1024);

    // combined scales (row scale / 127^2) for this lane's 4 gate rows
    float scv[4];
#pragma unroll
    for (int g = 0; g < 4; g++)
        scv[g] = sc[d * 1024 + g * 256 + j];

    const int goffs = ((b * 2 + d) * 256 + j) * 4;        // + tt*131072
    const size_t iob = (size_t)b * NS * 512 + d * 256 + j; // + tt*512
    const int hwr = quad * 256 + j;                        // LDS write
    const int hrd = l15 * 64 + quad * 16;                  // LDS read (16B chunk)
    const int rr = l15 & 3;

    float cst = 0.f;

    // pipeline: G for step 0
    int tt = d ? (NS - 1) : 0;
    bf16x4 gv = *(const bf16x4*)(G + (size_t)tt * 131072 + goffs);

    for (int t = 0; t < NS; t++) {
        const int rb = (t + 1) & 1, wbuf = t & 1;
        const int tt_n = d ? (NS - 2 - t) : (t + 1);

        // prefetch next step's G (independent of everything this step)
        bf16x4 gn = gv;
        if (t < NS - 1)
            gn = *(const bf16x4*)(G + (size_t)tt_n * 131072 + goffs);

        // MFMA: gates = Whh_i8 . h_i8 with K-quarter row remap
        v4i acc[4] = {};
        if (t > 0) {
            v4i chunk = *(const v4i*)&hs[rb][hrd];
#pragma unroll
            for (int kt = 0; kt < 4; kt++) {
                v4i a;
                a[0] = (rr == kt) ? chunk[0] : 0;
                a[1] = (rr == kt) ? chunk[1] : 0;
                a[2] = (rr == kt) ? chunk[2] : 0;
                a[3] = (rr == kt) ? chunk[3] : 0;
#pragma unroll
                for (int g = 0; g < 4; g++)
                    acc[g] = __builtin_amdgcn_mfma_i32_16x16x64_i8(a, Wr[g][kt], acc[g], 0, 0, 0);
            }
        }

        // elementwise: exactly 1 cell/lane (batch=quad, hidden j)
        int si = acc[0][0] + acc[0][1] + acc[0][2] + acc[0][3];
        int sf = acc[1][0] + acc[1][1] + acc[1][2] + acc[1][3];
        int sg = acc[2][0] + acc[2][1] + acc[2][2] + acc[2][3];
        int so = acc[3][0] + acc[3][1] + acc[3][2] + acc[3][3];
        float pi = (float)si * scv[0] + (float)gv[0];
        float pf = (float)sf * scv[1] + (float)gv[1];
        float pg = (float)sg * scv[2] + (float)gv[2];
        float po = (float)so * scv[3] + (float)gv[3];
        float ig = sigm(pi), fg = sigm(pf), gc = tanh_(pg), og = sigm(po);
        float c = fg * cst + ig * gc;
        cst = c;
        float hh = og * tanh_(c);
        io_out[iob + (size_t)tt * 512] = (bf16)hh;
        int hq = (int)__builtin_rintf(hh * 127.f);
        hs[wbuf][hwr] = (signed char)hq;

        gv = gn;
        tt = tt_n;
        __syncthreads();   // h(t) visible for step t+1
    }
}

// ---------------- GCN banded adjacency matmul -> bf16 ----------------
__global__ void k_banded(const float* __restrict__ x, const float* __restrict__ mask,
                         bf16* __restrict__ outb) {
    int t  = blockIdx.x * 256 + threadIdx.x;  // < 64*512*64
    int bs = t >> 6;
    int c4 = (t & 63) << 2;
    int s = bs & (NS - 1);
    float m  = mask[bs];
    float mn = (s < NS - 1) ? mask[bs + 1] : 0.f;
    float mp = (s > 0)      ? mask[bs - 1] : 0.f;
    float rs = m * (mp + mn) + 1e-8f;
    float cn = m * mn / rs;
    float cp = m * mp / rs;
    f32x4 vn = {}, vp = {};
    if (s < NS - 1) vn = *(const f32x4*)(x + (size_t)(bs + 1) * NGC + c4);
    if (s > 0)      vp = *(const f32x4*)(x + (size_t)(bs - 1) * NGC + c4);
    bf16x4 o;
#pragma unroll
    for (int i = 0; i < 4; i++) o[i] = (bf16)(cn * vn[i] + cp * vp[i]);
    *(bf16x4*)(outb + (size_t)bs * NGC + c4) = o;
}

// ---------------- GCN residual + layernorm + relu (one wave per row) ----------------
__global__ void k_gcnpost(const float* __restrict__ gemm_out, const float* __restrict__ x,
                          const float* __restrict__ gamma, const float* __restrict__ beta,
                          float* __restrict__ outx) {
    int row  = blockIdx.x * 4 + (threadIdx.x >> 6);
    int lane = threadIdx.x & 63;
    const float* h  = gemm_out + (size_t)row * NGC;
    const float* xr = x + (size_t)row * NGC;
    f32x4 hv = *(const f32x4*)(h + lane * 4);
    f32x4 xv = *(const f32x4*)(xr + lane * 4);
    f32x4 v;
#pragma unroll
    for (int i = 0; i < 4; i++) v[i] = hv[i] + xv[i];
    float sum = v[0] + v[1] + v[2] + v[3];
#pragma unroll
    for (int off = 32; off >= 1; off >>= 1) sum += __shfl_xor(sum, off);
    float mu = sum * (1.f / NGC);
    float sq = 0.f;
    f32x4 dv;
#pragma unroll
    for (int i = 0; i < 4; i++) { dv[i] = v[i] - mu; sq += dv[i] * dv[i]; }
#pragma unroll
    for (int off = 32; off >= 1; off >>= 1) sq += __shfl_xor(sq, off);
    float inv = rsqrtf(sq * (1.f / NGC) + 1e-5f);
    f32x4 o;
#pragma unroll
    for (int i = 0; i < 4; i++) {
        int c = lane * 4 + i;
        float y = dv[i] * inv * gamma[c] + beta[c];
        o[i] = fmaxf(y, 0.f);
    }
    *(f32x4*)(outx + (size_t)row * NGC + lane * 4) = o;
}

// ---------------- masked mean pooling ----------------
__global__ void k_pool_bf16(const bf16* __restrict__ src, const float* __restrict__ mask,
                            float* __restrict__ feat) {  // F = 512
    int b = blockIdx.x, f = threadIdx.x;
    float acc = 0.f, dm = 0.f;
    for (int t = 0; t < NS; t++) {
        float m = mask[b * NS + t];
        acc += m * (float)src[((size_t)b * NS + t) * 512 + f];
        dm += m;
    }
    feat[b * 512 + f] = acc / fmaxf(dm, 1e-8f);
}
__global__ void k_pool_f32(const float* __restrict__ src, const float* __restrict__ mask,
                           float* __restrict__ feat) {  // F = 256
    int b = blockIdx.x, f = threadIdx.x;
    float acc = 0.f, dm = 0.f;
    for (int t = 0; t < NS; t++) {
        float m = mask[b * NS + t];
        acc += m * src[((size_t)b * NS + t) * NGC + f];
        dm += m;
    }
    feat[b * NGC + f] = acc / fmaxf(dm, 1e-8f);
}

// ---------------- fused head ----------------
__global__ __launch_bounds__(512)
void k_head(const float* __restrict__ lfeat, const float* __restrict__ gfeat,
            const float* __restrict__ aux,
            const float* __restrict__ fc1W, const float* __restrict__ fc1b,
            const float* __restrict__ fc2W, const float* __restrict__ fc2b,
            const float* __restrict__ h0W, const float* __restrict__ h0b,
            const float* __restrict__ h1W, const float* __restrict__ h1b,
            float* __restrict__ out) {
    __shared__ float fused[FUSION];
    __shared__ float s1[512];
    __shared__ float s2[256];
    int m = blockIdx.x, tid = threadIdx.x;
    if (tid < 512) fused[tid] = lfeat[m * 512 + tid];
    if (tid < 256) fused[512 + tid] = gfeat[m * 256 + tid];
    if (tid < 6)   fused[768 + tid] = aux[m * 6 + tid];
    __syncthreads();
    {
        float a = fc1b[tid];
        const float* w = fc1W + (size_t)tid * FUSION;
        for (int k = 0; k < FUSION; k++) a += w[k] * fused[k];
        s1[tid] = fmaxf(a, 0.f);
    }
    __syncthreads();
    if (tid < 256) {
        float a = fc2b[tid];
        const float* w = fc2W + (size_t)tid * 512;
        for (int k = 0; k < 512; k++) a += w[k] * s1[k];
        s2[tid] = fmaxf(a, 0.f);
    }
    __syncthreads();
    if (tid < 15) {
        if (tid < 10) {
            float a = h0b[tid];
            const float* w = h0W + (size_t)tid * 256;
            for (int k = 0; k < 256; k++) a += w[k] * s2[k];
            out[m * 10 + tid] = a;
        } else {
            int n = tid - 10;
            float a = h1b[n];
            const float* w = h1W + (size_t)n * 256;
            for (int k = 0; k < 256; k++) a += w[k] * s2[k];
            out[640 + m * 5 + n] = a;
        }
    }
}

// ---------------- host launcher ----------------
extern "C" void kernel_launch(void* const* d_in, const int* in_sizes, int n_in,
                              void* d_out, int out_size, void* d_ws, size_t ws_size,
                              hipStream_t stream) {
    const int*   seq   = (const int*)d_in[0];
    const float* mask  = (const float*)d_in[1];
    const float* aux   = (const float*)d_in[2];
    const float* table = (const float*)d_in[3];
    const float* Wih0  = (const float*)d_in[4];
    const float* Whh0  = (const float*)d_in[5];
    const float* b0    = (const float*)d_in[6];
    const float* WihL  = (const float*)d_in[7];
    const float* WhhL  = (const float*)d_in[8];
    const float* bL    = (const float*)d_in[9];
    const float* gcnW  = (const float*)d_in[10];
    const float* gcnb  = (const float*)d_in[11];
    const float* gcnG  = (const float*)d_in[12];
    const float* gcnBe = (const float*)d_in[13];
    const float* fc1W  = (const float*)d_in[14];
    const float* fc1b  = (const float*)d_in[15];
    const float* fc2W  = (const float*)d_in[16];
    const float* fc2b  = (const float*)d_in[17];
    const float* h0W   = (const float*)d_in[18];
    const float* h0b   = (const float*)d_in[19];
    const float* h1W   = (const float*)d_in[20];
    const float* h1b   = (const float*)d_in[21];
    float* outp = (float*)d_out;

    char* ws = (char*)d_ws;
    const size_t MROWS = (size_t)NB * NS;          // 32768
    float* emb_f32 = (float*)(ws + 0);             // 33.55 MB
    bf16*  emb_b   = (bf16*) (ws + 33554432);      // 16.78 MB (dead after L0 gemm)
    signed char* Wp8 = (signed char*)(ws + 33554432); // 2.62 MB, aliases emb_b
    float* wsc     = (float*)(ws + 36175872);      // 40 KB scales
    bf16*  io0     = (bf16*) (ws + 50331648);      // 33.55 MB
    bf16*  io1     = (bf16*) (ws + 83886080);      // 33.55 MB
    char*  Greg    =          ws + 117440512;      // 128 MiB (G; GCN scratch aliases here)
    bf16*  G       = (bf16*)  Greg;
    float* lfeat   = (float*)(ws + 251658240);     // 128 KB
    float* gfeat   = (float*)(ws + 251789312);     // 64 KB
    // GCN aliases (used before G):
    float* gcnA  = (float*)(Greg + 0);
    float* gcnB_ = (float*)(Greg + 33554432);
    float* ggemm = (float*)(Greg + 67108864);
    bf16*  gtmp  = (bf16*) (Greg + 100663296);
    (void)ws_size; (void)n_in; (void)in_sizes; (void)out_size;

    // embedding
    k_embed<<<dim3(8192), dim3(256), 0, stream>>>(seq, table, emb_f32, emb_b);

    // ---- GCN stack ----
    const float* xcur = emb_f32;
    float* xnxt[3] = {gcnA, gcnB_, gcnA};
    for (int i = 0; i < 3; i++) {
        k_banded<<<dim3(8192), dim3(256), 0, stream>>>(xcur, mask, gtmp);
        k_gemm<<<dim3((MROWS / 128) * (NGC / 128)), dim3(256), 0, stream>>>(
            gtmp, gcnW + (size_t)i * NGC * NGC, gcnb + i * NGC, ggemm,
            (int)MROWS, NGC, NGC, 0);
        k_gcnpost<<<dim3(8192), dim3(256), 0, stream>>>(
            ggemm, xcur, gcnG + i * NGC, gcnBe + i * NGC, xnxt[i]);
        xcur = xnxt[i];
    }
    k_pool_f32<<<dim3(NB), dim3(NGC), 0, stream>>>(xcur, mask, gfeat);

    // ---- BiLSTM stack ----
    const bf16* Xin = emb_b;
    int Kin = NE;
    bf16* ios[2] = {io0, io1};
    for (int l = 0; l < NL; l++) {
        const float* wih  = l ? (WihL + (size_t)(l - 1) * 2 * 1024 * 512) : Wih0;
        const float* bias = l ? (bL + (size_t)(l - 1) * 2048) : b0;
        k_gemm<<<dim3((MROWS / 128) * (2048 / 128)), dim3(256), 0, stream>>>(
            Xin, wih, bias, G, (int)MROWS, 2048, Kin, 3);
        if (l == 0) {
            // emb_b consumed; quantize+pack all layers' Whh to int8 fragment layout
            k_prep_i8<<<dim3(2560), dim3(256), 0, stream>>>(Whh0, WhhL, Wp8, wsc);
        }
        bf16* lio = ios[l & 1];
        k_lstm_i8<<<dim3(32), dim3(1024), 0, stream>>>(
            G, Wp8 + (size_t)l * 524288, wsc + (size_t)l * 2048, lio);
        Xin = lio;
        Kin = 512;
    }
    k_pool_bf16<<<dim3(NB), dim3(512), 0, stream>>>(ios[(NL - 1) & 1], mask, lfeat);

    // ---- fused head ----
    k_head<<<dim3(NB), dim3(512), 0, stream>>>(
        lfeat, gfeat, aux, fc1W, fc1b, fc2W, fc2b, h0W, h0b, h1W, h1b, outp);
}

// Round 6
// 4165.509 us; speedup vs baseline: 7.6990x; 1.0432x over previous
//
#include <hip/hip_runtime.h>
#include <stdint.h>
#include <stddef.h>

// ---------------- types ----------------
typedef __bf16 bf16;
typedef __bf16 bf16x8 __attribute__((ext_vector_type(8)));
typedef __bf16 bf16x4 __attribute__((ext_vector_type(4)));
typedef float  f32x4  __attribute__((ext_vector_type(4)));
typedef int    v4i    __attribute__((ext_vector_type(4)));

// ---------------- problem constants ----------------
#define NB   64      // batch
#define NS   512     // seq len
#define NE   256     // embed dim
#define NH   256     // lstm hidden
#define NL   5       // lstm layers
#define NGC  256     // gcn hidden
#define FUSION 774   // 2H + GC + 6

__device__ __forceinline__ float sigm(float x) {
    return __fdividef(1.f, 1.f + __expf(-x));
}
__device__ __forceinline__ float tanh_(float x) {
    return __fdividef(2.f, 1.f + __expf(-2.f * x)) - 1.f;
}

// ---------------- f32 -> bf16 convert (vector of 4) ----------------
__global__ void k_cvt(const float* __restrict__ src, bf16* __restrict__ dst, int n4) {
    int i = blockIdx.x * 256 + threadIdx.x;
    if (i >= n4) return;
    f32x4 v = ((const f32x4*)src)[i];
    bf16x4 o;
    o[0] = (bf16)v[0]; o[1] = (bf16)v[1]; o[2] = (bf16)v[2]; o[3] = (bf16)v[3];
    ((bf16x4*)dst)[i] = o;
}

// ---------------- embedding gather (f32 + bf16 copies) ----------------
__global__ void k_embed(const int* __restrict__ seq, const float* __restrict__ table,
                        float* __restrict__ ef, bf16* __restrict__ eb) {
    int t  = blockIdx.x * 256 + threadIdx.x;  // < 64*512*64
    int bs = t >> 6;
    int c4 = (t & 63) << 2;
    int row = seq[bs];
    f32x4 v = *(const f32x4*)(table + (size_t)row * NE + c4);
    *(f32x4*)(ef + (size_t)bs * NE + c4) = v;
    bf16x4 o;
    o[0] = (bf16)v[0]; o[1] = (bf16)v[1]; o[2] = (bf16)v[2]; o[3] = (bf16)v[3];
    *(bf16x4*)(eb + (size_t)bs * NE + c4) = o;
}

// ---------------- bf16 MFMA GEMM: C[M,N] = A[M,K] * W[N,K]^T + bias (both bf16) ----------------
// out_mode: 0 = f32 [M,N]; 3 = bf16 gate-interleaved [tt][b][d][j][g] with
//           m = b*NS+tt, col = d*1024 + g*256 + j
__global__ __launch_bounds__(256, 2)
void k_gemm(const bf16* __restrict__ A, const bf16* __restrict__ W,
            const float* __restrict__ bias, void* __restrict__ Cout,
            int M, int N, int K, int out_mode) {
    __shared__ bf16 sA[128 * 72];
    __shared__ bf16 sB[128 * 72];
    const int mblk = M >> 7;
    int bm = blockIdx.x % mblk;
    int bn = blockIdx.x / mblk;
    int m0 = bm << 7, n0 = bn << 7;
    int tid  = threadIdx.x;
    int wave = tid >> 6, lane = tid & 63;
    int wm = wave >> 1, wn = wave & 1;
    int l15 = lane & 15, quad = lane >> 4;

    f32x4 acc[4][4] = {};

    for (int k0 = 0; k0 < K; k0 += 64) {
        int r = tid >> 1, co = (tid & 1) * 32;
        {
            const bf16* src = A + (size_t)(m0 + r) * K + k0 + co;
            bf16* dst = sA + r * 72 + co;
            *(uint4*)(dst +  0) = *(const uint4*)(src +  0);
            *(uint4*)(dst +  8) = *(const uint4*)(src +  8);
            *(uint4*)(dst + 16) = *(const uint4*)(src + 16);
            *(uint4*)(dst + 24) = *(const uint4*)(src + 24);
        }
        {
            const bf16* src = W + (size_t)(n0 + r) * K + k0 + co;
            bf16* dst = sB + r * 72 + co;
            *(uint4*)(dst +  0) = *(const uint4*)(src +  0);
            *(uint4*)(dst +  8) = *(const uint4*)(src +  8);
            *(uint4*)(dst + 16) = *(const uint4*)(src + 16);
            *(uint4*)(dst + 24) = *(const uint4*)(src + 24);
        }
        __syncthreads();
#pragma unroll
        for (int kk = 0; kk < 2; kk++) {
            bf16x8 af[4], bfr[4];
#pragma unroll
            for (int mt = 0; mt < 4; mt++)
                af[mt] = *(const bf16x8*)(sA + (wm * 64 + mt * 16 + l15) * 72 + kk * 32 + quad * 8);
#pragma unroll
            for (int nt = 0; nt < 4; nt++)
                bfr[nt] = *(const bf16x8*)(sB + (wn * 64 + nt * 16 + l15) * 72 + kk * 32 + quad * 8);
#pragma unroll
            for (int mt = 0; mt < 4; mt++)
#pragma unroll
                for (int nt = 0; nt < 4; nt++)
                    acc[mt][nt] = __builtin_amdgcn_mfma_f32_16x16x32_bf16(af[mt], bfr[nt], acc[mt][nt], 0, 0, 0);
        }
        __syncthreads();
    }
#pragma unroll
    for (int mt = 0; mt < 4; mt++) {
#pragma unroll
        for (int nt = 0; nt < 4; nt++) {
            int col = n0 + wn * 64 + nt * 16 + l15;
            float bv = bias[col];
            int row0 = m0 + wm * 64 + mt * 16 + quad * 4;
#pragma unroll
            for (int r4 = 0; r4 < 4; r4++) {
                float v = acc[mt][nt][r4] + bv;
                int r = row0 + r4;
                if (out_mode == 3) {
                    int tt = r & (NS - 1), b = r >> 9;
                    int dd = col >> 10, g = (col >> 8) & 3, j = col & 255;
                    ((bf16*)Cout)[(((((size_t)tt * 64 + b) * 2 + dd) * 256 + j) << 2) + g] = (bf16)v;
                } else {
                    ((float*)Cout)[(size_t)r * N + col] = v;
                }
            }
        }
    }
}

// ---------------- Whh int8 pre-pack + per-row scales ----------------
// cell index fi = (w*4 + g)*4 + kt (w = j-slice of 16, g = gate, kt = K-window of 64):
// frag-lane q*16+l15r holds row (g*256 + w*16 + l15r), bytes k = kt*64 + q*16 + j'.
__global__ void k_prep_i8(const float* __restrict__ Whh0, const float* __restrict__ WhhL,
                          signed char* __restrict__ Wp8, float* __restrict__ scales) {
    int gw = blockIdx.x * 4 + (threadIdx.x >> 6);   // row id < 10240
    int lane = threadIdx.x & 63;
    int row = gw & 1023;
    int d = (gw >> 10) & 1;
    int layer = gw >> 11;
    const float* src = (layer == 0)
        ? (Whh0 + ((size_t)d * 1024 + row) * 256)
        : (WhhL + (((size_t)(layer - 1) * 2 + d) * 1024 + row) * 256);
    f32x4 v = *(const f32x4*)(src + lane * 4);
    float am = fmaxf(fmaxf(fabsf(v[0]), fabsf(v[1])), fmaxf(fabsf(v[2]), fabsf(v[3])));
#pragma unroll
    for (int off = 32; off >= 1; off >>= 1) am = fmaxf(am, __shfl_xor(am, off));
    am = fmaxf(am, 1e-8f);
    float inv = 127.f / am;
    int q0 = (int)__builtin_rintf(v[0] * inv);
    int q1 = (int)__builtin_rintf(v[1] * inv);
    int q2 = (int)__builtin_rintf(v[2] * inv);
    int q3 = (int)__builtin_rintf(v[3] * inv);
    uint32_t packed = (q0 & 255) | ((q1 & 255) << 8) | ((q2 & 255) << 16) | ((q3 & 255) << 24);
    int g = row >> 8, rem = row & 255;
    int w = rem >> 4, l15r = rem & 15;
    int k = lane * 4;
    int kt = k >> 6, q = (k >> 4) & 3, j = k & 15;
    size_t cell = ((size_t)layer * 2 + d) * 256 + (w * 4 + g) * 4 + kt;
    *(uint32_t*)(Wp8 + cell * 1024 + (q * 16 + l15r) * 16 + j) = packed;
    if (lane == 0)
        scales[((size_t)layer * 2 + d) * 1024 + row] = am * (1.f / (127.f * 127.f));
}

// ---------------- LSTM recurrence: 32 blocks x 1024 threads, pinned-resident i8 weights ----------------
// __launch_bounds__(1024,4): 4 waves/EU -> 128-VGPR cap, 1 block/CU.
// Empty inline-asm pin on each weight cell makes the loaded values non-rematerializable,
// forcing true register residency (no per-step L2 restream).
// h chunks XOR-swizzled in LDS: read chunk c -> addr (c ^ ((c>>2)&3))*16 (2-way, free).
__global__ __launch_bounds__(1024, 4)
void k_lstm_i8(const bf16* __restrict__ G,     // [S][64][2][256][4]
               const signed char* __restrict__ Wp8,  // [2][256][1024] for this layer
               const float* __restrict__ sc,   // [2][1024]
               bf16* __restrict__ io_out)      // [64][S][512]
{
    __shared__ signed char hs[2][1024];   // h dbuf: 64 chunks of 16B, swizzled

    const int d  = blockIdx.x & 1;
    const int bg = blockIdx.x >> 1;       // 0..15
    const int tid = threadIdx.x;
    const int w = tid >> 6, lane = tid & 63;
    const int l15 = lane & 15, quad = lane >> 4;
    const int b = bg * 4 + quad;          // global batch handled by this lane
    const int j = w * 16 + l15;           // hidden index handled by this lane

    // resident weights: 4 gates x 4 K-windows x 16B = 64 VGPRs
    const signed char* wb = Wp8 + ((size_t)d * 256 + w * 16) * 1024 + lane * 16;
    v4i Wr[4][4];
#pragma unroll
    for (int g = 0; g < 4; g++)
#pragma unroll
        for (int kt = 0; kt < 4; kt++)
            Wr[g][kt] = *(const v4i*)(wb + (g * 4 + kt) * 1024);
    // pin: values become asm outputs -> cannot be rematerialized by reloading
#pragma unroll
    for (int g = 0; g < 4; g++)
#pragma unroll
        for (int kt = 0; kt < 4; kt++)
            asm volatile("" : "+v"(Wr[g][kt]));

    // combined scales (row scale / 127^2) for this lane's 4 gate rows
    float scv[4];
#pragma unroll
    for (int g = 0; g < 4; g++)
        scv[g] = sc[d * 1024 + g * 256 + j];

    const int goffs = ((b * 2 + d) * 256 + j) * 4;        // + tt*131072
    const size_t iob = (size_t)b * NS * 512 + d * 256 + j; // + tt*512
    // LDS write: chunk cw = quad*16 + w, byte l15; swizzle low2(cw) ^= (w>>2)&3
    const int wsw = (w & ~3) | ((w & 3) ^ ((w >> 2) & 3));
    const int hwr = quad * 256 + wsw * 16 + l15;
    // LDS read: chunk c = l15*4 + quad -> swizzled (c>>2)&3 = l15&3
    const int hrd = (l15 * 4 + (quad ^ (l15 & 3))) * 16;
    const int rr = l15 & 3;

    float cst = 0.f;

    // pipeline: G for step 0
    int tt = d ? (NS - 1) : 0;
    bf16x4 gv = *(const bf16x4*)(G + (size_t)tt * 131072 + goffs);

    for (int t = 0; t < NS; t++) {
        const int rb = (t + 1) & 1, wbuf = t & 1;
        const int tt_n = d ? (NS - 2 - t) : (t + 1);

        // prefetch next step's G (independent of everything this step)
        bf16x4 gn = gv;
        if (t < NS - 1)
            gn = *(const bf16x4*)(G + (size_t)tt_n * 131072 + goffs);

        // MFMA: gates = Whh_i8 . h_i8 with K-quarter row remap
        v4i acc[4] = {};
        if (t > 0) {
            v4i chunk = *(const v4i*)&hs[rb][hrd];
#pragma unroll
            for (int kt = 0; kt < 4; kt++) {
                v4i a;
                a[0] = (rr == kt) ? chunk[0] : 0;
                a[1] = (rr == kt) ? chunk[1] : 0;
                a[2] = (rr == kt) ? chunk[2] : 0;
                a[3] = (rr == kt) ? chunk[3] : 0;
#pragma unroll
                for (int g = 0; g < 4; g++)
                    acc[g] = __builtin_amdgcn_mfma_i32_16x16x64_i8(a, Wr[g][kt], acc[g], 0, 0, 0);
            }
        }

        // elementwise: exactly 1 cell/lane (batch=quad group, hidden j)
        int si = acc[0][0] + acc[0][1] + acc[0][2] + acc[0][3];
        int sf = acc[1][0] + acc[1][1] + acc[1][2] + acc[1][3];
        int sg = acc[2][0] + acc[2][1] + acc[2][2] + acc[2][3];
        int so = acc[3][0] + acc[3][1] + acc[3][2] + acc[3][3];
        float pi = (float)si * scv[0] + (float)gv[0];
        float pf = (float)sf * scv[1] + (float)gv[1];
        float pg = (float)sg * scv[2] + (float)gv[2];
        float po = (float)so * scv[3] + (float)gv[3];
        float ig = sigm(pi), fg = sigm(pf), gc = tanh_(pg), og = sigm(po);
        float c = fg * cst + ig * gc;
        cst = c;
        float hh = og * tanh_(c);
        io_out[iob + (size_t)tt * 512] = (bf16)hh;
        int hq = (int)__builtin_rintf(hh * 127.f);
        hs[wbuf][hwr] = (signed char)hq;

        gv = gn;
        tt = tt_n;
        __syncthreads();   // h(t) visible for step t+1
    }
}

// ---------------- GCN banded adjacency matmul -> bf16 ----------------
__global__ void k_banded(const float* __restrict__ x, const float* __restrict__ mask,
                         bf16* __restrict__ outb) {
    int t  = blockIdx.x * 256 + threadIdx.x;  // < 64*512*64
    int bs = t >> 6;
    int c4 = (t & 63) << 2;
    int s = bs & (NS - 1);
    float m  = mask[bs];
    float mn = (s < NS - 1) ? mask[bs + 1] : 0.f;
    float mp = (s > 0)      ? mask[bs - 1] : 0.f;
    float rs = m * (mp + mn) + 1e-8f;
    float cn = m * mn / rs;
    float cp = m * mp / rs;
    f32x4 vn = {}, vp = {};
    if (s < NS - 1) vn = *(const f32x4*)(x + (size_t)(bs + 1) * NGC + c4);
    if (s > 0)      vp = *(const f32x4*)(x + (size_t)(bs - 1) * NGC + c4);
    bf16x4 o;
#pragma unroll
    for (int i = 0; i < 4; i++) o[i] = (bf16)(cn * vn[i] + cp * vp[i]);
    *(bf16x4*)(outb + (size_t)bs * NGC + c4) = o;
}

// ---------------- GCN residual + layernorm + relu (one wave per row) ----------------
__global__ void k_gcnpost(const float* __restrict__ gemm_out, const float* __restrict__ x,
                          const float* __restrict__ gamma, const float* __restrict__ beta,
                          float* __restrict__ outx) {
    int row  = blockIdx.x * 4 + (threadIdx.x >> 6);
    int lane = threadIdx.x & 63;
    const float* h  = gemm_out + (size_t)row * NGC;
    const float* xr = x + (size_t)row * NGC;
    f32x4 hv = *(const f32x4*)(h + lane * 4);
    f32x4 xv = *(const f32x4*)(xr + lane * 4);
    f32x4 v;
#pragma unroll
    for (int i = 0; i < 4; i++) v[i] = hv[i] + xv[i];
    float sum = v[0] + v[1] + v[2] + v[3];
#pragma unroll
    for (int off = 32; off >= 1; off >>= 1) sum += __shfl_xor(sum, off);
    float mu = sum * (1.f / NGC);
    float sq = 0.f;
    f32x4 dv;
#pragma unroll
    for (int i = 0; i < 4; i++) { dv[i] = v[i] - mu; sq += dv[i] * dv[i]; }
#pragma unroll
    for (int off = 32; off >= 1; off >>= 1) sq += __shfl_xor(sq, off);
    float inv = rsqrtf(sq * (1.f / NGC) + 1e-5f);
    f32x4 o;
#pragma unroll
    for (int i = 0; i < 4; i++) {
        int c = lane * 4 + i;
        float y = dv[i] * inv * gamma[c] + beta[c];
        o[i] = fmaxf(y, 0.f);
    }
    *(f32x4*)(outx + (size_t)row * NGC + lane * 4) = o;
}

// ---------------- masked mean pooling ----------------
__global__ void k_pool_bf16(const bf16* __restrict__ src, const float* __restrict__ mask,
                            float* __restrict__ feat) {  // F = 512
    int b = blockIdx.x, f = threadIdx.x;
    float acc = 0.f, dm = 0.f;
    for (int t = 0; t < NS; t++) {
        float m = mask[b * NS + t];
        acc += m * (float)src[((size_t)b * NS + t) * 512 + f];
        dm += m;
    }
    feat[b * 512 + f] = acc / fmaxf(dm, 1e-8f);
}
__global__ void k_pool_f32(const float* __restrict__ src, const float* __restrict__ mask,
                           float* __restrict__ feat) {  // F = 256
    int b = blockIdx.x, f = threadIdx.x;
    float acc = 0.f, dm = 0.f;
    for (int t = 0; t < NS; t++) {
        float m = mask[b * NS + t];
        acc += m * src[((size_t)b * NS + t) * NGC + f];
        dm += m;
    }
    feat[b * NGC + f] = acc / fmaxf(dm, 1e-8f);
}

// ---------------- fused head ----------------
__global__ __launch_bounds__(512)
void k_head(const float* __restrict__ lfeat, const float* __restrict__ gfeat,
            const float* __restrict__ aux,
            const float* __restrict__ fc1W, const float* __restrict__ fc1b,
            const float* __restrict__ fc2W, const float* __restrict__ fc2b,
            const float* __restrict__ h0W, const float* __restrict__ h0b,
            const float* __restrict__ h1W, const float* __restrict__ h1b,
            float* __restrict__ out) {
    __shared__ float fused[FUSION];
    __shared__ float s1[512];
    __shared__ float s2[256];
    int m = blockIdx.x, tid = threadIdx.x;
    if (tid < 512) fused[tid] = lfeat[m * 512 + tid];
    if (tid < 256) fused[512 + tid] = gfeat[m * 256 + tid];
    if (tid < 6)   fused[768 + tid] = aux[m * 6 + tid];
    __syncthreads();
    {
        float a = fc1b[tid];
        const float* w = fc1W + (size_t)tid * FUSION;
        for (int k = 0; k < FUSION; k++) a += w[k] * fused[k];
        s1[tid] = fmaxf(a, 0.f);
    }
    __syncthreads();
    if (tid < 256) {
        float a = fc2b[tid];
        const float* w = fc2W + (size_t)tid * 512;
        for (int k = 0; k < 512; k++) a += w[k] * s1[k];
        s2[tid] = fmaxf(a, 0.f);
    }
    __syncthreads();
    if (tid < 15) {
        if (tid < 10) {
            float a = h0b[tid];
            const float* w = h0W + (size_t)tid * 256;
            for (int k = 0; k < 256; k++) a += w[k] * s2[k];
            out[m * 10 + tid] = a;
        } else {
            int n = tid - 10;
            float a = h1b[n];
            const float* w = h1W + (size_t)n * 256;
            for (int k = 0; k < 256; k++) a += w[k] * s2[k];
            out[640 + m * 5 + n] = a;
        }
    }
}

// ---------------- host launcher ----------------
extern "C" void kernel_launch(void* const* d_in, const int* in_sizes, int n_in,
                              void* d_out, int out_size, void* d_ws, size_t ws_size,
                              hipStream_t stream) {
    const int*   seq   = (const int*)d_in[0];
    const float* mask  = (const float*)d_in[1];
    const float* aux   = (const float*)d_in[2];
    const float* table = (const float*)d_in[3];
    const float* Wih0  = (const float*)d_in[4];
    const float* Whh0  = (const float*)d_in[5];
    const float* b0    = (const float*)d_in[6];
    const float* WihL  = (const float*)d_in[7];
    const float* WhhL  = (const float*)d_in[8];
    const float* bL    = (const float*)d_in[9];
    const float* gcnW  = (const float*)d_in[10];
    const float* gcnb  = (const float*)d_in[11];
    const float* gcnG  = (const float*)d_in[12];
    const float* gcnBe = (const float*)d_in[13];
    const float* fc1W  = (const float*)d_in[14];
    const float* fc1b  = (const float*)d_in[15];
    const float* fc2W  = (const float*)d_in[16];
    const float* fc2b  = (const float*)d_in[17];
    const float* h0W   = (const float*)d_in[18];
    const float* h0b   = (const float*)d_in[19];
    const float* h1W   = (const float*)d_in[20];
    const float* h1b   = (const float*)d_in[21];
    float* outp = (float*)d_out;

    char* ws = (char*)d_ws;
    const size_t MROWS = (size_t)NB * NS;          // 32768
    // region 0 (0..33.55 MB): packed weights
    signed char* Wp8 = (signed char*)(ws + 0);     // 2.62 MB
    float* wsc     = (float*)(ws + 2621440);       // 40 KB
    bf16*  Wbf     = (bf16*) (ws + 2662400);       // 9.83 MB: Wih0|WihL|gcnW (bf16)
    bf16*  wb0     = Wbf;                          // [2048][256]
    bf16*  wbL     = Wbf + 524288;                 // 4 x [2048][512]
    bf16*  wgcn    = Wbf + 524288 + 4194304;       // 3 x [256][256]
    bf16*  emb_b   = (bf16*) (ws + 33554432);      // 16.78 MB
    bf16*  io0     = (bf16*) (ws + 50331648);      // 33.55 MB
    bf16*  io1     = (bf16*) (ws + 83886080);      // 33.55 MB
    char*  Greg    =          ws + 117440512;      // 134.2 MB (G; GCN scratch aliases)
    bf16*  G       = (bf16*)  Greg;
    float* lfeat   = (float*)(ws + 251658240);     // 128 KB
    float* gfeat   = (float*)(ws + 251789312);     // 64 KB
    // GCN aliases (all inside Greg, used before G is written):
    float* gcnA  = (float*)(Greg + 0);             // f32 emb / x buffers
    float* gcnB_ = (float*)(Greg + 33554432);
    float* ggemm = (float*)(Greg + 67108864);
    bf16*  gtmp  = (bf16*) (Greg + 100663296);
    (void)ws_size; (void)n_in; (void)in_sizes; (void)out_size;

    // ---- weight prep (same every call) ----
    k_cvt<<<dim3(512),  dim3(256), 0, stream>>>(Wih0, wb0, 131072);
    k_cvt<<<dim3(4096), dim3(256), 0, stream>>>(WihL, wbL, 1048576);
    k_cvt<<<dim3(192),  dim3(256), 0, stream>>>(gcnW, wgcn, 49152);
    k_prep_i8<<<dim3(2560), dim3(256), 0, stream>>>(Whh0, WhhL, Wp8, wsc);

    // embedding (f32 copy into gcnA, bf16 copy into emb_b)
    k_embed<<<dim3(8192), dim3(256), 0, stream>>>(seq, table, gcnA, emb_b);

    // ---- GCN stack ----
    const float* xcur = gcnA;
    float* xnxt[3] = {gcnB_, gcnA, gcnB_};
    for (int i = 0; i < 3; i++) {
        k_banded<<<dim3(8192), dim3(256), 0, stream>>>(xcur, mask, gtmp);
        k_gemm<<<dim3((MROWS / 128) * (NGC / 128)), dim3(256), 0, stream>>>(
            gtmp, wgcn + (size_t)i * NGC * NGC, gcnb + i * NGC, ggemm,
            (int)MROWS, NGC, NGC, 0);
        k_gcnpost<<<dim3(8192), dim3(256), 0, stream>>>(
            ggemm, xcur, gcnG + i * NGC, gcnBe + i * NGC, xnxt[i]);
        xcur = xnxt[i];
    }
    k_pool_f32<<<dim3(NB), dim3(NGC), 0, stream>>>(xcur, mask, gfeat);

    // ---- BiLSTM stack ----
    const bf16* Xin = emb_b;
    int Kin = NE;
    bf16* ios[2] = {io0, io1};
    for (int l = 0; l < NL; l++) {
        const bf16* wih = l ? (wbL + (size_t)(l - 1) * 1048576) : wb0;
        const float* bias = l ? (bL + (size_t)(l - 1) * 2048) : b0;
        k_gemm<<<dim3((MROWS / 128) * (2048 / 128)), dim3(256), 0, stream>>>(
            Xin, wih, bias, G, (int)MROWS, 2048, Kin, 3);
        bf16* lio = ios[l & 1];
        k_lstm_i8<<<dim3(32), dim3(1024), 0, stream>>>(
            G, Wp8 + (size_t)l * 524288, wsc + (size_t)l * 2048, lio);
        Xin = lio;
        Kin = 512;
    }
    k_pool_bf16<<<dim3(NB), dim3(512), 0, stream>>>(ios[(NL - 1) & 1], mask, lfeat);

    // ---- fused head ----
    k_head<<<dim3(NB), dim3(512), 0, stream>>>(
        lfeat, gfeat, aux, fc1W, fc1b, fc2W, fc2b, h0W, h0b, h1W, h1b, outp);
}